// Round 2
// baseline (1255.770 us; speedup 1.0000x reference)
//
#include <hip/hip_runtime.h>
#include <hip/hip_bf16.h>
#include <stdint.h>

#define NB 400
#define NC 151
#define DX 4096
#define DE 200
#define DP 128
#define DH 512
#define KREP 4424   // 4096 + 200 + 128

__device__ __forceinline__ uint32_t f2ord(float f) {
  uint32_t u = __float_as_uint(f);
  return (u & 0x80000000u) ? ~u : (u | 0x80000000u);
}

// ---------------------------------------------------------------------------
// k_embed: per-row softmax(predict_logits) @ obj_embed_w, and the pos path
// (linear -> BN -> linear -> relu). One block per row.
// ---------------------------------------------------------------------------
__global__ __launch_bounds__(256) void k_embed(
    const float* __restrict__ logits, const float* __restrict__ obj_embed_w,
    const float* __restrict__ pos_input, const float* __restrict__ w_pos1,
    const float* __restrict__ b_pos1, const float* __restrict__ bn_gamma,
    const float* __restrict__ bn_beta, const float* __restrict__ bn_mean,
    const float* __restrict__ bn_var, const float* __restrict__ w_pos2,
    const float* __restrict__ b_pos2,
    float* __restrict__ obj_embed, float* __restrict__ pos_embed) {
  int r = blockIdx.x, t = threadIdx.x;
  __shared__ float p[NC];
  __shared__ float red[256];
  __shared__ float hb[32];

  float v = (t < NC) ? logits[r * NC + t] : -INFINITY;
  red[t] = v; __syncthreads();
  for (int s = 128; s > 0; s >>= 1) { if (t < s) red[t] = fmaxf(red[t], red[t + s]); __syncthreads(); }
  float m = red[0]; __syncthreads();
  float e = (t < NC) ? expf(v - m) : 0.f;
  red[t] = e; __syncthreads();
  for (int s = 128; s > 0; s >>= 1) { if (t < s) red[t] += red[t + s]; __syncthreads(); }
  float sum = red[0];
  if (t < NC) p[t] = e / sum;

  if (t < 32) {
    float acc = b_pos1[t];
    for (int k = 0; k < 9; k++) acc += pos_input[r * 9 + k] * w_pos1[k * 32 + t];
    acc = (acc - bn_mean[t]) / sqrtf(bn_var[t] + 1e-5f) * bn_gamma[t] + bn_beta[t];
    hb[t] = acc;
  }
  __syncthreads();

  if (t < DE) {
    float acc = 0.f;
    for (int k = 0; k < NC; k++) acc += p[k] * obj_embed_w[k * DE + t];
    obj_embed[r * DE + t] = acc;
  }
  if (t < DP) {
    float acc = b_pos2[t];
    for (int k = 0; k < 32; k++) acc += hb[k] * w_pos2[k * DP + t];
    pos_embed[r * DP + t] = fmaxf(acc, 0.f);
  }
}

// ---------------------------------------------------------------------------
// k_overlap: bit-packed IoU>=0.5 matrix. One block per class c: stage
// boxes[:, c, :] in LDS, each wave handles source boxes b = wave, wave+4, ...
// ov_bits[(b*NC+c)*8 + chunk] = 64-bit mask over target rows j. any_ov byte
// per (b,c): popcount>1 (self always overlaps).
// ---------------------------------------------------------------------------
__global__ __launch_bounds__(256) void k_overlap(
    const float* __restrict__ boxes, uint64_t* __restrict__ ov_bits,
    uint8_t* __restrict__ any_ov) {
  int c = blockIdx.x;
  int t = threadIdx.x;
  __shared__ float4 bx[NB];
  const float4* bp4 = (const float4*)boxes;
  for (int j = t; j < NB; j += 256) bx[j] = bp4[j * NC + c];
  __syncthreads();

  int wave = t >> 6, lane = t & 63;
  for (int b = wave; b < NB; b += 4) {
    float4 A = bx[b];
    float areaA = (A.z - A.x + 1.f) * (A.w - A.y + 1.f);
    int cnt = 0;
    for (int chunk = 0; chunk < 7; chunk++) {
      int j = chunk * 64 + lane;
      bool ov = false;
      if (j < NB) {
        float4 B = bx[j];
        float x1 = fmaxf(A.x, B.x), y1 = fmaxf(A.y, B.y);
        float x2 = fminf(A.z, B.z), y2 = fminf(A.w, B.w);
        float iw = fmaxf(x2 - x1 + 1.f, 0.f), ih = fmaxf(y2 - y1 + 1.f, 0.f);
        float inter = iw * ih;
        float areaB = (B.z - B.x + 1.f) * (B.w - B.y + 1.f);
        float uni = areaA + areaB - inter;
        ov = (inter / uni) >= 0.5f;
      }
      uint64_t mask = __ballot(ov);
      if (lane == 0) ov_bits[((size_t)(b * NC + c) << 3) + chunk] = mask;
      cnt += __popcll(mask);
    }
    if (lane == 0) any_ov[b * NC + c] = (cnt > 1) ? 1 : 0;
  }
}

// ---------------------------------------------------------------------------
// k_gemm: out[400,512] = A @ w + bias, A synthesized from segments (fp32 out).
// mode 0: A = [x | obj_embed | pos_embed], no relu.
// mode 1: A = [x | pos_embed | obj_embed2_w[labels]], relu.
// 32x32 block tile, K-tile 32, 2x2 per thread.
// ---------------------------------------------------------------------------
__global__ __launch_bounds__(256) void k_gemm(
    const float* __restrict__ x, const float* __restrict__ seg1,
    const float* __restrict__ seg2, const int* __restrict__ labels,
    const float* __restrict__ w, const float* __restrict__ bias,
    float* __restrict__ out_f, int mode) {
  __shared__ float As[32][33];
  __shared__ float Bs[32][33];
  int tid = threadIdx.x;
  int m0 = blockIdx.y * 32, n0 = blockIdx.x * 32;
  int tm = (tid >> 4) << 1, tn = (tid & 15) << 1;
  float a00 = 0.f, a01 = 0.f, a10 = 0.f, a11 = 0.f;

  for (int k0 = 0; k0 < KREP; k0 += 32) {
#pragma unroll
    for (int i = 0; i < 4; i++) {
      int idx = tid + i * 256;
      int rr = idx >> 5, cc = idx & 31;
      int row = m0 + rr, k = k0 + cc;
      float av = 0.f;
      if (row < NB && k < KREP) {
        if (k < DX) av = x[(size_t)row * DX + k];
        else if (mode == 0) {
          if (k < DX + DE) av = seg1[row * DE + (k - DX)];
          else av = seg2[row * DP + (k - DX - DE)];
        } else {
          if (k < DX + DP) av = seg1[row * DP + (k - DX)];
          else av = seg2[labels[row] * DE + (k - DX - DP)];
        }
      }
      As[rr][cc] = av;
      float bv = 0.f;
      if (k0 + rr < KREP) bv = w[(size_t)(k0 + rr) * DH + n0 + cc];
      Bs[rr][cc] = bv;
    }
    __syncthreads();
#pragma unroll
    for (int kk = 0; kk < 32; kk++) {
      float av0 = As[tm][kk], av1 = As[tm + 1][kk];
      float bv0 = Bs[kk][tn], bv1 = Bs[kk][tn + 1];
      a00 += av0 * bv0; a01 += av0 * bv1;
      a10 += av1 * bv0; a11 += av1 * bv1;
    }
    __syncthreads();
  }

  int row0 = m0 + tm, col0 = n0 + tn;
  float b0 = bias[col0], b1 = bias[col0 + 1];
  float r00 = a00 + b0, r01 = a01 + b1, r10 = a10 + b0, r11 = a11 + b1;
  if (mode == 1) {
    r00 = fmaxf(r00, 0.f); r01 = fmaxf(r01, 0.f);
    r10 = fmaxf(r10, 0.f); r11 = fmaxf(r11, 0.f);
  }
  if (row0 < NB)     { out_f[row0 * DH + col0] = r00;       out_f[row0 * DH + col0 + 1] = r01; }
  if (row0 + 1 < NB) { out_f[(row0 + 1) * DH + col0] = r10; out_f[(row0 + 1) * DH + col0 + 1] = r11; }
}

// ---------------------------------------------------------------------------
// k_dists: obj_dists row = hidden_row @ w_out + b_out; write fp32 to d_out;
// softmax -> scores (col0 = -1); per-row (max, argmin-col) for NMS.
// ---------------------------------------------------------------------------
__global__ __launch_bounds__(256) void k_dists(
    const float* __restrict__ hidden, const float* __restrict__ w_out,
    const float* __restrict__ b_out, float* __restrict__ out_dists,
    float* __restrict__ scores, float* __restrict__ row_max,
    uint32_t* __restrict__ row_arg) {
  int r = blockIdx.x, t = threadIdx.x;
  __shared__ float h[DH];
  __shared__ float red[256];
  __shared__ float sval[NC];
  __shared__ uint64_t red64[4];
  h[t] = hidden[r * DH + t];
  h[t + 256] = hidden[r * DH + t + 256];
  __syncthreads();

  float acc = -INFINITY;
  if (t < NC) {
    acc = b_out[t];
    for (int k = 0; k < DH; k++) acc += h[k] * w_out[k * NC + t];
    out_dists[r * NC + t] = acc;
  }
  red[t] = (t < NC) ? acc : -INFINITY; __syncthreads();
  for (int s = 128; s > 0; s >>= 1) { if (t < s) red[t] = fmaxf(red[t], red[t + s]); __syncthreads(); }
  float mx = red[0]; __syncthreads();
  float e = (t < NC) ? expf(acc - mx) : 0.f;
  red[t] = e; __syncthreads();
  for (int s = 128; s > 0; s >>= 1) { if (t < s) red[t] += red[t + s]; __syncthreads(); }
  float sum = red[0];

  float sc = (t == 0) ? -1.0f : e / sum;
  if (t < NC) { scores[r * NC + t] = sc; sval[t] = sc; }

  uint64_t key = (t < NC) ? (((uint64_t)f2ord(sc) << 16) | (uint64_t)(255 - t)) : 0ull;
  for (int off = 32; off; off >>= 1) { uint64_t o = __shfl_down(key, off, 64); if (o > key) key = o; }
  if ((t & 63) == 0) red64[t >> 6] = key;
  __syncthreads();
  if (t == 0) {
    uint64_t best = red64[0];
    for (int i = 1; i < 4; i++) if (red64[i] > best) best = red64[i];
    int col = 255 - (int)(best & 0xFF);
    row_arg[r] = (uint32_t)col;
    row_max[r] = sval[col];
  }
}

// ---------------------------------------------------------------------------
// k_nms: sequential greedy NMS, single block. Exact flat-argmax semantics via
// per-row (max, min-col) in LDS + cross-row (max, min-row) u64 key reduce.
// Global scores array is kept exact (zeros on suppression, -1 rows on
// removal) so rescans are always correct. Preds written as fp32 label values.
// ---------------------------------------------------------------------------
__global__ __launch_bounds__(512) void k_nms(
    const uint64_t* __restrict__ ov_bits, const uint8_t* __restrict__ any_ov,
    float* __restrict__ scores, const float* __restrict__ row_max_g,
    const uint32_t* __restrict__ row_arg_g, int* __restrict__ labels_g,
    float* __restrict__ out_preds) {
  int t = threadIdx.x;
  __shared__ float rmax[NB];
  __shared__ uint32_t rarg[NB];
  __shared__ int labels[NB];
  __shared__ uint64_t red64[8];
  __shared__ uint64_t anybits[944];   // 60400 bits, padded
  __shared__ uint64_t ovrow[8];
  __shared__ int s_b;

  if (t < NB) { rmax[t] = row_max_g[t]; rarg[t] = row_arg_g[t]; labels[t] = 0; }
  {
    int wv = t >> 6, lane = t & 63;
    for (int wd = wv; wd < 944; wd += 8) {
      int idx = wd * 64 + lane;
      bool f = (idx < NB * NC) && (any_ov[idx] != 0);
      uint64_t m = __ballot(f);
      if (lane == 0) anybits[wd] = m;
    }
  }
  __syncthreads();

  for (int step = 0; step < NB; step++) {
    uint64_t key = (t < NB) ? (((uint64_t)f2ord(rmax[t]) << 16) | (uint64_t)(511 - t)) : 0ull;
    for (int off = 32; off; off >>= 1) { uint64_t o = __shfl_down(key, off, 64); if (o > key) key = o; }
    if ((t & 63) == 0) red64[t >> 6] = key;
    __syncthreads();
    if (t == 0) {
      uint64_t best = red64[0];
      for (int i = 1; i < 8; i++) if (red64[i] > best) best = red64[i];
      s_b = 511 - (int)(best & 0xFFFF);
    }
    __syncthreads();
    int b = s_b;
    int cls = (int)rarg[b];
    if (t == 0) labels[b] = cls;
    int flat = b * NC + cls;
    bool any = (anybits[flat >> 6] >> (flat & 63)) & 1;
    if (any) {
      if (t < 7) ovrow[t] = ov_bits[((size_t)flat << 3) + t];
      __syncthreads();
      if (t < NB && t != b && ((ovrow[t >> 6] >> (t & 63)) & 1)) {
        scores[t * NC + cls] = 0.f;
        if (rarg[t] == (uint32_t)cls) {
          // entry removed was this row's argmax -> exact rescan
          float bm = -2.f; int ba = 0;
          for (int c2 = 0; c2 < NC; c2++) {
            float vv = (c2 == cls) ? 0.f : scores[t * NC + c2];
            if (vv > bm) { bm = vv; ba = c2; }
          }
          rmax[t] = bm; rarg[t] = (uint32_t)ba;
        } else if (0.f > rmax[t]) {
          rmax[t] = 0.f; rarg[t] = (uint32_t)cls;   // resurrection of removed row
        } else if (0.f == rmax[t] && (uint32_t)cls < rarg[t]) {
          rarg[t] = (uint32_t)cls;
        }
      }
    }
    // removal: keep global row exact (-1 everywhere, overriding the 0 at cls)
    if (t < NC) scores[b * NC + t] = -1.0f;
    if (t == 0) { rmax[b] = -1.0f; rarg[b] = 0; }
    __syncthreads();
  }

  if (t < NB) {
    labels_g[t] = labels[t];
    out_preds[t] = (float)labels[t];
  }
}

// ---------------------------------------------------------------------------
extern "C" void kernel_launch(void* const* d_in, const int* in_sizes, int n_in,
                              void* d_out, int out_size, void* d_ws, size_t ws_size,
                              hipStream_t stream) {
  const float* x            = (const float*)d_in[0];
  const float* logits       = (const float*)d_in[1];
  const float* pos_input    = (const float*)d_in[2];
  const float* boxes        = (const float*)d_in[3];
  const float* obj_embed_w  = (const float*)d_in[4];
  const float* obj_embed2_w = (const float*)d_in[5];
  const float* w_pos1       = (const float*)d_in[6];
  const float* b_pos1       = (const float*)d_in[7];
  const float* bn_gamma     = (const float*)d_in[8];
  const float* bn_beta      = (const float*)d_in[9];
  const float* bn_mean      = (const float*)d_in[10];
  const float* bn_var       = (const float*)d_in[11];
  const float* w_pos2       = (const float*)d_in[12];
  const float* b_pos2       = (const float*)d_in[13];
  const float* w_lin        = (const float*)d_in[14];
  const float* b_lin        = (const float*)d_in[15];
  const float* w_out        = (const float*)d_in[16];
  const float* b_out        = (const float*)d_in[17];
  const float* w_fc         = (const float*)d_in[18];
  const float* b_fc         = (const float*)d_in[19];

  float* ws         = (float*)d_ws;
  float* obj_embed  = ws;                      // 400*200
  float* pos_embed  = obj_embed + NB * DE;     // 400*128
  float* hidden     = pos_embed + NB * DP;     // 400*512
  float* scores     = hidden + NB * DH;        // 400*151
  float* row_max    = scores + NB * NC;        // 400
  uint32_t* row_arg = (uint32_t*)(row_max + NB);       // 400
  int* labels       = (int*)(row_arg + NB);            // 400
  uint8_t* any_ov   = (uint8_t*)(labels + NB);         // 60400 bytes (pad 60416)
  uint64_t* ov_bits = (uint64_t*)(any_ov + 60416);     // 400*151*8 u64 = 3.87 MB

  float* out       = (float*)d_out;
  float* out_dists = out;                 // 400*151
  float* out_preds = out + NB * NC;       // 400
  float* out_edge  = out + NB * NC + NB;  // 400*512

  k_embed<<<NB, 256, 0, stream>>>(logits, obj_embed_w, pos_input, w_pos1, b_pos1,
                                  bn_gamma, bn_beta, bn_mean, bn_var, w_pos2, b_pos2,
                                  obj_embed, pos_embed);
  k_overlap<<<NC, 256, 0, stream>>>(boxes, ov_bits, any_ov);
  k_gemm<<<dim3(16, 13), 256, 0, stream>>>(x, obj_embed, pos_embed, labels,
                                           w_lin, b_lin, hidden, 0);
  k_dists<<<NB, 256, 0, stream>>>(hidden, w_out, b_out, out_dists, scores, row_max, row_arg);
  k_nms<<<1, 512, 0, stream>>>(ov_bits, any_ov, scores, row_max, row_arg, labels, out_preds);
  k_gemm<<<dim3(16, 13), 256, 0, stream>>>(x, pos_embed, obj_embed2_w, labels,
                                           w_fc, b_fc, out_edge, 1);
}

// Round 3
// 1053.130 us; speedup vs baseline: 1.1924x; 1.1924x over previous
//
#include <hip/hip_runtime.h>
#include <hip/hip_bf16.h>
#include <stdint.h>

#define NB 400
#define NC 151
#define DX 4096
#define DE 200
#define DP 128
#define DH 512
#define KREP 4424   // 4096 + 200 + 128
#define SPLITK 4
#define KCHUNK 1106 // 4424/4
#define SLOTS 7     // 7*64 = 448 >= 400 rows per lane-slot grid

__device__ __forceinline__ uint32_t f2ord(float f) {
  uint32_t u = __float_as_uint(f);
  return (u & 0x80000000u) ? ~u : (u | 0x80000000u);
}

// ---------------------------------------------------------------------------
// k_embed: per-row softmax(predict_logits) @ obj_embed_w, and the pos path
// (linear -> BN -> linear -> relu). One block per row.
// ---------------------------------------------------------------------------
__global__ __launch_bounds__(256) void k_embed(
    const float* __restrict__ logits, const float* __restrict__ obj_embed_w,
    const float* __restrict__ pos_input, const float* __restrict__ w_pos1,
    const float* __restrict__ b_pos1, const float* __restrict__ bn_gamma,
    const float* __restrict__ bn_beta, const float* __restrict__ bn_mean,
    const float* __restrict__ bn_var, const float* __restrict__ w_pos2,
    const float* __restrict__ b_pos2,
    float* __restrict__ obj_embed, float* __restrict__ pos_embed) {
  int r = blockIdx.x, t = threadIdx.x;
  __shared__ float p[NC];
  __shared__ float red[256];
  __shared__ float hb[32];

  float v = (t < NC) ? logits[r * NC + t] : -INFINITY;
  red[t] = v; __syncthreads();
  for (int s = 128; s > 0; s >>= 1) { if (t < s) red[t] = fmaxf(red[t], red[t + s]); __syncthreads(); }
  float m = red[0]; __syncthreads();
  float e = (t < NC) ? expf(v - m) : 0.f;
  red[t] = e; __syncthreads();
  for (int s = 128; s > 0; s >>= 1) { if (t < s) red[t] += red[t + s]; __syncthreads(); }
  float sum = red[0];
  if (t < NC) p[t] = e / sum;

  if (t < 32) {
    float acc = b_pos1[t];
    for (int k = 0; k < 9; k++) acc += pos_input[r * 9 + k] * w_pos1[k * 32 + t];
    acc = (acc - bn_mean[t]) / sqrtf(bn_var[t] + 1e-5f) * bn_gamma[t] + bn_beta[t];
    hb[t] = acc;
  }
  __syncthreads();

  if (t < DE) {
    float acc = 0.f;
    for (int k = 0; k < NC; k++) acc += p[k] * obj_embed_w[k * DE + t];
    obj_embed[r * DE + t] = acc;
  }
  if (t < DP) {
    float acc = b_pos2[t];
    for (int k = 0; k < 32; k++) acc += hb[k] * w_pos2[k * DP + t];
    pos_embed[r * DP + t] = fmaxf(acc, 0.f);
  }
}

// ---------------------------------------------------------------------------
// k_overlap: bit-packed IoU>=0.5 matrix. One block per class c.
// ov_bits[(b*NC+c)*8 + chunk] = 64-bit mask over target rows j.
// ---------------------------------------------------------------------------
__global__ __launch_bounds__(256) void k_overlap(
    const float* __restrict__ boxes, uint64_t* __restrict__ ov_bits) {
  int c = blockIdx.x;
  int t = threadIdx.x;
  __shared__ float4 bx[NB];
  const float4* bp4 = (const float4*)boxes;
  for (int j = t; j < NB; j += 256) bx[j] = bp4[j * NC + c];
  __syncthreads();

  int wave = t >> 6, lane = t & 63;
  for (int b = wave; b < NB; b += 4) {
    float4 A = bx[b];
    float areaA = (A.z - A.x + 1.f) * (A.w - A.y + 1.f);
    for (int chunk = 0; chunk < 7; chunk++) {
      int j = chunk * 64 + lane;
      bool ov = false;
      if (j < NB) {
        float4 B = bx[j];
        float x1 = fmaxf(A.x, B.x), y1 = fmaxf(A.y, B.y);
        float x2 = fminf(A.z, B.z), y2 = fminf(A.w, B.w);
        float iw = fmaxf(x2 - x1 + 1.f, 0.f), ih = fmaxf(y2 - y1 + 1.f, 0.f);
        float inter = iw * ih;
        float areaB = (B.z - B.x + 1.f) * (B.w - B.y + 1.f);
        float uni = areaA + areaB - inter;
        ov = (inter / uni) >= 0.5f;
      }
      uint64_t mask = __ballot(ov);
      if (lane == 0) ov_bits[((size_t)(b * NC + c) << 3) + chunk] = mask;
    }
  }
}

// ---------------------------------------------------------------------------
// k_gemm_pk: split-K partial GEMM. part[z][row][col] = A[row, kz..] @ w[kz.., col]
// mode 0: A = [x | obj_embed | pos_embed]; mode 1: A = [x | pos_embed | emb2[labels]]
// grid (16 n-tiles, 13 m-tiles, SPLITK). 32x32 tile, 2x2/thread, no bias here.
// ---------------------------------------------------------------------------
__global__ __launch_bounds__(256) void k_gemm_pk(
    const float* __restrict__ x, const float* __restrict__ seg1,
    const float* __restrict__ seg2, const int* __restrict__ labels,
    const float* __restrict__ w, float* __restrict__ part, int mode) {
  __shared__ float As[32][33];
  __shared__ float Bs[32][33];
  int tid = threadIdx.x;
  int m0 = blockIdx.y * 32, n0 = blockIdx.x * 32;
  int kbeg = blockIdx.z * KCHUNK;
  int kend = kbeg + KCHUNK;   // KCHUNK*SPLITK == KREP exactly
  int tm = (tid >> 4) << 1, tn = (tid & 15) << 1;
  float a00 = 0.f, a01 = 0.f, a10 = 0.f, a11 = 0.f;

  for (int k0 = kbeg; k0 < kend; k0 += 32) {
#pragma unroll
    for (int i = 0; i < 4; i++) {
      int idx = tid + i * 256;
      int rr = idx >> 5, cc = idx & 31;
      int row = m0 + rr, k = k0 + cc;
      float av = 0.f;
      if (row < NB && k < kend) {
        if (k < DX) av = x[(size_t)row * DX + k];
        else if (mode == 0) {
          if (k < DX + DE) av = seg1[row * DE + (k - DX)];
          else av = seg2[row * DP + (k - DX - DE)];
        } else {
          if (k < DX + DP) av = seg1[row * DP + (k - DX)];
          else av = seg2[labels[row] * DE + (k - DX - DP)];
        }
      }
      As[rr][cc] = av;
      float bv = 0.f;
      if (k0 + rr < kend) bv = w[(size_t)(k0 + rr) * DH + n0 + cc];
      Bs[rr][cc] = bv;
    }
    __syncthreads();
#pragma unroll
    for (int kk = 0; kk < 32; kk++) {
      float av0 = As[tm][kk], av1 = As[tm + 1][kk];
      float bv0 = Bs[kk][tn], bv1 = Bs[kk][tn + 1];
      a00 += av0 * bv0; a01 += av0 * bv1;
      a10 += av1 * bv0; a11 += av1 * bv1;
    }
    __syncthreads();
  }

  int row0 = m0 + tm, col0 = n0 + tn;
  float* base = part + (size_t)blockIdx.z * NB * DH;
  if (row0 < NB)     { base[row0 * DH + col0] = a00;       base[row0 * DH + col0 + 1] = a01; }
  if (row0 + 1 < NB) { base[(row0 + 1) * DH + col0] = a10; base[(row0 + 1) * DH + col0 + 1] = a11; }
}

// ---------------------------------------------------------------------------
// k_sumparts: out = sum_z part[z] + bias (opt relu). Deterministic fixed order.
// 400*512/4 = 51200 float4 elements -> 200 blocks of 256.
// ---------------------------------------------------------------------------
__global__ __launch_bounds__(256) void k_sumparts(
    const float* __restrict__ part, const float* __restrict__ bias,
    float* __restrict__ outp, int relu) {
  int i = blockIdx.x * 256 + threadIdx.x;   // float4 index over 400*512
  const float4* p4 = (const float4*)part;
  float4 a = p4[i];
  float4 b = p4[51200 + i];
  float4 c = p4[2 * 51200 + i];
  float4 d = p4[3 * 51200 + i];
  float4 bv = ((const float4*)bias)[i & 127];
  float4 r;
  r.x = a.x + b.x + c.x + d.x + bv.x;
  r.y = a.y + b.y + c.y + d.y + bv.y;
  r.z = a.z + b.z + c.z + d.z + bv.z;
  r.w = a.w + b.w + c.w + d.w + bv.w;
  if (relu) {
    r.x = fmaxf(r.x, 0.f); r.y = fmaxf(r.y, 0.f);
    r.z = fmaxf(r.z, 0.f); r.w = fmaxf(r.w, 0.f);
  }
  ((float4*)outp)[i] = r;
}

// ---------------------------------------------------------------------------
// k_dists: obj_dists row = hidden_row @ w_out + b_out; write fp32 to d_out;
// softmax -> scores (col0 = -1); per-row (max, argmin-col) for NMS.
// ---------------------------------------------------------------------------
__global__ __launch_bounds__(256) void k_dists(
    const float* __restrict__ hidden, const float* __restrict__ w_out,
    const float* __restrict__ b_out, float* __restrict__ out_dists,
    float* __restrict__ scores, float* __restrict__ row_max,
    uint32_t* __restrict__ row_arg) {
  int r = blockIdx.x, t = threadIdx.x;
  __shared__ float h[DH];
  __shared__ float red[256];
  __shared__ float sval[NC];
  __shared__ uint64_t red64[4];
  h[t] = hidden[r * DH + t];
  h[t + 256] = hidden[r * DH + t + 256];
  __syncthreads();

  float acc = -INFINITY;
  if (t < NC) {
    acc = b_out[t];
    for (int k = 0; k < DH; k++) acc += h[k] * w_out[k * NC + t];
    out_dists[r * NC + t] = acc;
  }
  red[t] = (t < NC) ? acc : -INFINITY; __syncthreads();
  for (int s = 128; s > 0; s >>= 1) { if (t < s) red[t] = fmaxf(red[t], red[t + s]); __syncthreads(); }
  float mx = red[0]; __syncthreads();
  float e = (t < NC) ? expf(acc - mx) : 0.f;
  red[t] = e; __syncthreads();
  for (int s = 128; s > 0; s >>= 1) { if (t < s) red[t] += red[t + s]; __syncthreads(); }
  float sum = red[0];

  float sc = (t == 0) ? -1.0f : e / sum;
  if (t < NC) { scores[r * NC + t] = sc; sval[t] = sc; }

  uint64_t key = (t < NC) ? (((uint64_t)f2ord(sc) << 16) | (uint64_t)(255 - t)) : 0ull;
  for (int off = 32; off; off >>= 1) { uint64_t o = __shfl_down(key, off, 64); if (o > key) key = o; }
  if ((t & 63) == 0) red64[t >> 6] = key;
  __syncthreads();
  if (t == 0) {
    uint64_t best = red64[0];
    for (int i = 1; i < 4; i++) if (red64[i] > best) best = red64[i];
    int col = 255 - (int)(best & 0xFF);
    row_arg[r] = (uint32_t)col;
    row_max[r] = sval[col];
  }
}

// ---------------------------------------------------------------------------
// k_nms: single-WAVE greedy NMS, all state in registers. Lane L owns rows
// r = s*64+L (s<7). Per step: local argmax -> prefetch own candidate's ov row
// -> u64-key butterfly (score desc, row asc; cls rides as payload) -> shfl
// winner's prefetched words -> per-slot register updates. No barriers/LDS.
// Exact reference semantics incl. rescan + dead-row resurrection.
// ---------------------------------------------------------------------------
__global__ __launch_bounds__(64) void k_nms(
    const uint64_t* __restrict__ ov_bits, float* __restrict__ scores,
    const float* __restrict__ row_max_g, const uint32_t* __restrict__ row_arg_g,
    int* __restrict__ labels_g, float* __restrict__ out_preds) {
  int lane = threadIdx.x;
  float rmax[SLOTS];
  int rarg[SLOTS];
#pragma unroll
  for (int s = 0; s < SLOTS; s++) {
    int r = s * 64 + lane;
    if (r < NB) { rmax[s] = row_max_g[r]; rarg[s] = (int)row_arg_g[r]; }
    else        { rmax[s] = -2.f; rarg[s] = 0; }
  }

  for (int step = 0; step < NB; step++) {
    // 1. local argmax over my 7 slots: key = (score | 511-r | cls)
    uint64_t best = 0;
#pragma unroll
    for (int s = 0; s < SLOTS; s++) {
      int r = s * 64 + lane;
      uint64_t key = ((uint64_t)f2ord(rmax[s]) << 32) |
                     ((uint64_t)(511 - r) << 16) | (uint64_t)rarg[s];
      if (key > best) best = key;
    }
    // 2. prefetch MY candidate's overlap row (hidden under the butterfly)
    int myb = 511 - (int)((best >> 16) & 0x1FF);
    int myc = (int)(best & 0xFFFF);
    const uint64_t* prow = ov_bits + (((size_t)(myb * NC + myc)) << 3);
    uint64_t pf[SLOTS];
#pragma unroll
    for (int s = 0; s < SLOTS; s++) pf[s] = prow[s];
    // 3. butterfly max across 64 lanes
#pragma unroll
    for (int off = 1; off < 64; off <<= 1) {
      uint64_t o = (uint64_t)__shfl_xor((unsigned long long)best, off, 64);
      if (o > best) best = o;
    }
    int b = 511 - (int)((best >> 16) & 0x1FF);
    int cls = (int)(best & 0xFFFF);
    int wl = b & 63;  // winner lane (its local candidate == global winner)
    uint64_t ow[SLOTS];
#pragma unroll
    for (int s = 0; s < SLOTS; s++)
      ow[s] = (uint64_t)__shfl((unsigned long long)pf[s], wl, 64);

    // 4. per-slot updates
#pragma unroll
    for (int s = 0; s < SLOTS; s++) {
      int r = s * 64 + lane;
      bool bit = (ow[s] >> lane) & 1;
      if (r == b) {
        rmax[s] = -1.f; rarg[s] = 0;
        labels_g[b] = cls;
        out_preds[b] = (float)cls;
      } else if (bit) {
        scores[r * NC + cls] = 0.f;
        if (rarg[s] == cls) {
          // suppressed entry was this row's argmax -> exact rescan
          float bm = -2.f; int ba = 0;
          for (int c2 = 0; c2 < NC; c2++) {
            float vv = (c2 == cls) ? 0.f : scores[r * NC + c2];
            if (vv > bm) { bm = vv; ba = c2; }
          }
          rmax[s] = bm; rarg[s] = ba;
        } else if (rmax[s] < -0.5f) {
          rmax[s] = 0.f; rarg[s] = cls;      // dead-row resurrection
        } else if (rmax[s] == 0.f && cls < rarg[s]) {
          rarg[s] = cls;                      // equal-zero tie -> min col
        }
      }
    }
    // 5. removal: keep global row exact (-1 everywhere) for future rescans
    for (int c = lane; c < NC; c += 64) scores[b * NC + c] = -1.f;
  }
}

// ---------------------------------------------------------------------------
extern "C" void kernel_launch(void* const* d_in, const int* in_sizes, int n_in,
                              void* d_out, int out_size, void* d_ws, size_t ws_size,
                              hipStream_t stream) {
  const float* x            = (const float*)d_in[0];
  const float* logits       = (const float*)d_in[1];
  const float* pos_input    = (const float*)d_in[2];
  const float* boxes        = (const float*)d_in[3];
  const float* obj_embed_w  = (const float*)d_in[4];
  const float* obj_embed2_w = (const float*)d_in[5];
  const float* w_pos1       = (const float*)d_in[6];
  const float* b_pos1       = (const float*)d_in[7];
  const float* bn_gamma     = (const float*)d_in[8];
  const float* bn_beta      = (const float*)d_in[9];
  const float* bn_mean      = (const float*)d_in[10];
  const float* bn_var       = (const float*)d_in[11];
  const float* w_pos2       = (const float*)d_in[12];
  const float* b_pos2       = (const float*)d_in[13];
  const float* w_lin        = (const float*)d_in[14];
  const float* b_lin        = (const float*)d_in[15];
  const float* w_out        = (const float*)d_in[16];
  const float* b_out        = (const float*)d_in[17];
  const float* w_fc         = (const float*)d_in[18];
  const float* b_fc         = (const float*)d_in[19];

  float* ws         = (float*)d_ws;
  float* obj_embed  = ws;                      // 80000 f
  float* pos_embed  = obj_embed + NB * DE;     // 51200 f
  float* hidden     = pos_embed + NB * DP;     // 204800 f
  float* scores     = hidden + NB * DH;        // 60400 f
  float* row_max    = scores + NB * NC;        // 400 f
  uint32_t* row_arg = (uint32_t*)(row_max + NB);       // 400
  int* labels       = (int*)(row_arg + NB);            // 400
  // union region (3.87 MB): ov_bits lives here between k_overlap and k_nms;
  // split-K partials (3.28 MB) reuse it before (gemm1) and after (gemm2).
  float* uregion    = (float*)(labels + NB);           // ws + 397600 floats
  uint64_t* ov_bits = (uint64_t*)uregion;
  float* part       = uregion;

  float* out       = (float*)d_out;
  float* out_dists = out;                 // 400*151
  float* out_preds = out + NB * NC;       // 400
  float* out_edge  = out + NB * NC + NB;  // 400*512

  k_embed<<<NB, 256, 0, stream>>>(logits, obj_embed_w, pos_input, w_pos1, b_pos1,
                                  bn_gamma, bn_beta, bn_mean, bn_var, w_pos2, b_pos2,
                                  obj_embed, pos_embed);
  k_gemm_pk<<<dim3(16, 13, SPLITK), 256, 0, stream>>>(x, obj_embed, pos_embed, labels,
                                                      w_lin, part, 0);
  k_sumparts<<<200, 256, 0, stream>>>(part, b_lin, hidden, 0);
  k_overlap<<<NC, 256, 0, stream>>>(boxes, ov_bits);
  k_dists<<<NB, 256, 0, stream>>>(hidden, w_out, b_out, out_dists, scores, row_max, row_arg);
  k_nms<<<1, 64, 0, stream>>>(ov_bits, scores, row_max, row_arg, labels, out_preds);
  k_gemm_pk<<<dim3(16, 13, SPLITK), 256, 0, stream>>>(x, pos_embed, obj_embed2_w, labels,
                                                      w_fc, part, 1);
  k_sumparts<<<200, 256, 0, stream>>>(part, b_fc, out_edge, 1);
}

// Round 4
// 994.832 us; speedup vs baseline: 1.2623x; 1.0586x over previous
//
#include <hip/hip_runtime.h>
#include <hip/hip_bf16.h>
#include <stdint.h>

#define NB 400
#define NC 151
#define DX 4096
#define DE 200
#define DP 128
#define DH 512
#define KREP 4424   // 4096 + 200 + 128
#define TAILW 328   // DE + DP
#define MPAD 416    // 13*32 rows, padded
#define SPLITK 8
#define TILES 139   // ceil(4424/32), last tile is 8 wide
#define SLOTS 7     // 7*64 = 448 >= 400

__device__ __forceinline__ uint32_t f2ord(float f) {
  uint32_t u = __float_as_uint(f);
  return (u & 0x80000000u) ? ~u : (u | 0x80000000u);
}

// ---------------------------------------------------------------------------
// k_embed: softmax(logits) @ obj_embed_w and pos path; writes DIRECTLY into
// the packed tail buffers: tail1 = [obj_embed | pos_embed], tail2[:,0:128] =
// pos_embed. Rows 400..415 zero-filled (padding for unguarded float4 loads).
// ---------------------------------------------------------------------------
__global__ __launch_bounds__(256) void k_embed(
    const float* __restrict__ logits, const float* __restrict__ obj_embed_w,
    const float* __restrict__ pos_input, const float* __restrict__ w_pos1,
    const float* __restrict__ b_pos1, const float* __restrict__ bn_gamma,
    const float* __restrict__ bn_beta, const float* __restrict__ bn_mean,
    const float* __restrict__ bn_var, const float* __restrict__ w_pos2,
    const float* __restrict__ b_pos2,
    float* __restrict__ tail1, float* __restrict__ tail2) {
  int r = blockIdx.x, t = threadIdx.x;
  if (r >= NB) {            // zero pad rows (uniform whole-block branch)
    if (t < TAILW) { tail1[r * TAILW + t] = 0.f; tail2[r * TAILW + t] = 0.f; }
    return;
  }
  __shared__ float p[NC];
  __shared__ float red[256];
  __shared__ float hb[32];

  float v = (t < NC) ? logits[r * NC + t] : -INFINITY;
  red[t] = v; __syncthreads();
  for (int s = 128; s > 0; s >>= 1) { if (t < s) red[t] = fmaxf(red[t], red[t + s]); __syncthreads(); }
  float m = red[0]; __syncthreads();
  float e = (t < NC) ? expf(v - m) : 0.f;
  red[t] = e; __syncthreads();
  for (int s = 128; s > 0; s >>= 1) { if (t < s) red[t] += red[t + s]; __syncthreads(); }
  float sum = red[0];
  if (t < NC) p[t] = e / sum;

  if (t < 32) {
    float acc = b_pos1[t];
    for (int k = 0; k < 9; k++) acc += pos_input[r * 9 + k] * w_pos1[k * 32 + t];
    acc = (acc - bn_mean[t]) / sqrtf(bn_var[t] + 1e-5f) * bn_gamma[t] + bn_beta[t];
    hb[t] = acc;
  }
  __syncthreads();

  if (t < DE) {
    float acc = 0.f;
    for (int k = 0; k < NC; k++) acc += p[k] * obj_embed_w[k * DE + t];
    tail1[r * TAILW + t] = acc;
  }
  if (t < DP) {
    float acc = b_pos2[t];
    for (int k = 0; k < 32; k++) acc += hb[k] * w_pos2[k * DP + t];
    float pe = fmaxf(acc, 0.f);
    tail1[r * TAILW + DE + t] = pe;
    tail2[r * TAILW + t] = pe;
  }
}

// ---------------------------------------------------------------------------
// k_tail2: after NMS, fill tail2[:,128:328] = obj_embed2_w[labels[r]].
// ---------------------------------------------------------------------------
__global__ __launch_bounds__(256) void k_tail2(
    const float* __restrict__ emb2, const int* __restrict__ labels,
    float* __restrict__ tail2) {
  int r = blockIdx.x, t = threadIdx.x;
  if (t < DE) tail2[r * TAILW + DP + t] = emb2[labels[r] * DE + t];
}

// ---------------------------------------------------------------------------
// k_overlap: bit-packed IoU>=0.5 matrix. One block per class c.
// ---------------------------------------------------------------------------
__global__ __launch_bounds__(256) void k_overlap(
    const float* __restrict__ boxes, uint64_t* __restrict__ ov_bits) {
  int c = blockIdx.x;
  int t = threadIdx.x;
  __shared__ float4 bx[NB];
  const float4* bp4 = (const float4*)boxes;
  for (int j = t; j < NB; j += 256) bx[j] = bp4[j * NC + c];
  __syncthreads();

  int wave = t >> 6, lane = t & 63;
  for (int b = wave; b < NB; b += 4) {
    float4 A = bx[b];
    float areaA = (A.z - A.x + 1.f) * (A.w - A.y + 1.f);
    for (int chunk = 0; chunk < 7; chunk++) {
      int j = chunk * 64 + lane;
      bool ov = false;
      if (j < NB) {
        float4 B = bx[j];
        float x1 = fmaxf(A.x, B.x), y1 = fmaxf(A.y, B.y);
        float x2 = fminf(A.z, B.z), y2 = fminf(A.w, B.w);
        float iw = fmaxf(x2 - x1 + 1.f, 0.f), ih = fmaxf(y2 - y1 + 1.f, 0.f);
        float inter = iw * ih;
        float areaB = (B.z - B.x + 1.f) * (B.w - B.y + 1.f);
        float uni = areaA + areaB - inter;
        ov = (inter / uni) >= 0.5f;
      }
      uint64_t mask = __ballot(ov);
      if (lane == 0) ov_bits[((size_t)(b * NC + c) << 3) + chunk] = mask;
    }
  }
}

// ---------------------------------------------------------------------------
// k_gemm_pk: split-K partial GEMM, all-float4 loads, register prefetch.
// A = [x(4096) | tail(328)] per row; tile 32(M)x64(N), BK=32, 2x4 microtile.
// grid (8 n, 13 m, 8 z). part[z] += A[:,ktiles(z)] @ w.
// ---------------------------------------------------------------------------
__global__ __launch_bounds__(256) void k_gemm_pk(
    const float* __restrict__ x, const float* __restrict__ tail,
    const float* __restrict__ w, float* __restrict__ part) {
  __shared__ __align__(16) float As[32][36];
  __shared__ __align__(16) float Bs[32][68];
  int tid = threadIdx.x;
  int n0 = blockIdx.x * 64, m0 = blockIdx.y * 32;
  int z = blockIdx.z;
  int tbeg = (z * TILES) / SPLITK, tend = ((z + 1) * TILES) / SPLITK;
  int ty = tid >> 4, tx = tid & 15;
  int a_r = tid >> 3, a_c = (tid & 7) << 2;
  int b_r = tid >> 4, b_c = (tid & 15) << 2;
  float4 acc0 = {0, 0, 0, 0}, acc1 = {0, 0, 0, 0};

  auto loadA = [&](int t) -> float4 {
    int k = t * 32 + a_c;
    int row = m0 + a_r;
    float4 v = {0, 0, 0, 0};
    if (k < KREP) {
      if (k < DX) { if (row < NB) v = *(const float4*)&x[(size_t)row * DX + k]; }
      else v = *(const float4*)&tail[row * TAILW + (k - DX)];   // rows padded to 416
    }
    return v;
  };
  auto loadB = [&](int t, int roff) -> float4 {
    int k = t * 32 + b_r + roff;
    float4 v = {0, 0, 0, 0};
    if (k < KREP) v = *(const float4*)&w[(size_t)k * DH + n0 + b_c];
    return v;
  };

  float4 pa = loadA(tbeg), pb0 = loadB(tbeg, 0), pb1 = loadB(tbeg, 16);
  for (int t = tbeg; t < tend; t++) {
    __syncthreads();
    *(float4*)&As[a_r][a_c] = pa;
    *(float4*)&Bs[b_r][b_c] = pb0;
    *(float4*)&Bs[b_r + 16][b_c] = pb1;
    __syncthreads();
    if (t + 1 < tend) { pa = loadA(t + 1); pb0 = loadB(t + 1, 0); pb1 = loadB(t + 1, 16); }
#pragma unroll
    for (int k4 = 0; k4 < 8; k4++) {
      float4 a0 = *(float4*)&As[ty * 2][k4 * 4];
      float4 a1 = *(float4*)&As[ty * 2 + 1][k4 * 4];
#pragma unroll
      for (int j = 0; j < 4; j++) {
        float4 bv = *(float4*)&Bs[k4 * 4 + j][tx * 4];
        float av0 = (&a0.x)[j], av1 = (&a1.x)[j];
        acc0.x += av0 * bv.x; acc0.y += av0 * bv.y; acc0.z += av0 * bv.z; acc0.w += av0 * bv.w;
        acc1.x += av1 * bv.x; acc1.y += av1 * bv.y; acc1.z += av1 * bv.z; acc1.w += av1 * bv.w;
      }
    }
  }
  int row0 = m0 + ty * 2, col = n0 + tx * 4;
  float* base = part + (size_t)z * NB * DH;
  if (row0 < NB)     *(float4*)&base[row0 * DH + col] = acc0;
  if (row0 + 1 < NB) *(float4*)&base[(row0 + 1) * DH + col] = acc1;
}

// ---------------------------------------------------------------------------
// k_sumparts: out = sum_z part[z] + bias (opt relu), fixed deterministic order.
// ---------------------------------------------------------------------------
__global__ __launch_bounds__(256) void k_sumparts(
    const float* __restrict__ part, const float* __restrict__ bias,
    float* __restrict__ outp, int relu) {
  int i = blockIdx.x * 256 + threadIdx.x;   // float4 index over 400*512
  const float4* p4 = (const float4*)part;
  float4 r = {0, 0, 0, 0};
#pragma unroll
  for (int zz = 0; zz < SPLITK; zz++) {
    float4 p = p4[(size_t)zz * 51200 + i];
    r.x += p.x; r.y += p.y; r.z += p.z; r.w += p.w;
  }
  float4 bv = ((const float4*)bias)[i & 127];
  r.x += bv.x; r.y += bv.y; r.z += bv.z; r.w += bv.w;
  if (relu) {
    r.x = fmaxf(r.x, 0.f); r.y = fmaxf(r.y, 0.f);
    r.z = fmaxf(r.z, 0.f); r.w = fmaxf(r.w, 0.f);
  }
  ((float4*)outp)[i] = r;
}

// ---------------------------------------------------------------------------
// k_dists: obj_dists row = hidden_row @ w_out + b_out -> d_out (fp32);
// softmax -> scores (col0=-1); per-row (max, min-col) for NMS.
// ---------------------------------------------------------------------------
__global__ __launch_bounds__(256) void k_dists(
    const float* __restrict__ hidden, const float* __restrict__ w_out,
    const float* __restrict__ b_out, float* __restrict__ out_dists,
    float* __restrict__ scores, float* __restrict__ row_max,
    uint32_t* __restrict__ row_arg) {
  int r = blockIdx.x, t = threadIdx.x;
  __shared__ float h[DH];
  __shared__ float red[256];
  __shared__ float sval[NC];
  __shared__ uint64_t red64[4];
  h[t] = hidden[r * DH + t];
  h[t + 256] = hidden[r * DH + t + 256];
  __syncthreads();

  float acc = -INFINITY;
  if (t < NC) {
    acc = b_out[t];
    for (int k = 0; k < DH; k++) acc += h[k] * w_out[k * NC + t];
    out_dists[r * NC + t] = acc;
  }
  red[t] = (t < NC) ? acc : -INFINITY; __syncthreads();
  for (int s = 128; s > 0; s >>= 1) { if (t < s) red[t] = fmaxf(red[t], red[t + s]); __syncthreads(); }
  float mx = red[0]; __syncthreads();
  float e = (t < NC) ? expf(acc - mx) : 0.f;
  red[t] = e; __syncthreads();
  for (int s = 128; s > 0; s >>= 1) { if (t < s) red[t] += red[t + s]; __syncthreads(); }
  float sum = red[0];

  float sc = (t == 0) ? -1.0f : e / sum;
  if (t < NC) { scores[r * NC + t] = sc; sval[t] = sc; }

  uint64_t key = (t < NC) ? (((uint64_t)f2ord(sc) << 16) | (uint64_t)(255 - t)) : 0ull;
  for (int off = 32; off; off >>= 1) { uint64_t o = __shfl_down(key, off, 64); if (o > key) key = o; }
  if ((t & 63) == 0) red64[t >> 6] = key;
  __syncthreads();
  if (t == 0) {
    uint64_t best = red64[0];
    for (int i = 1; i < 4; i++) if (red64[i] > best) best = red64[i];
    int col = 255 - (int)(best & 0xFF);
    row_arg[r] = (uint32_t)col;
    row_max[r] = sval[col];
  }
}

// ---------------------------------------------------------------------------
// k_nms: single-wave greedy NMS, register state. Per step: local argmax ->
// 6-round u64 butterfly -> lanes 0..6 fetch WINNER's overlap row (one
// dependent L2 load) -> 7 shfl broadcasts -> register updates. Exact ref
// semantics (min-row/min-col ties, rescan, dead-row resurrection).
// ---------------------------------------------------------------------------
__global__ __launch_bounds__(64) void k_nms(
    const uint64_t* __restrict__ ov_bits, float* __restrict__ scores,
    const float* __restrict__ row_max_g, const uint32_t* __restrict__ row_arg_g,
    int* __restrict__ labels_g, float* __restrict__ out_preds) {
  int lane = threadIdx.x;
  float rmax[SLOTS];
  int rarg[SLOTS];
#pragma unroll
  for (int s = 0; s < SLOTS; s++) {
    int r = s * 64 + lane;
    if (r < NB) {
      rmax[s] = row_max_g[r]; rarg[s] = (int)row_arg_g[r];
      labels_g[r] = 0; out_preds[r] = 0.f;   // default (ref inits labels to 0)
    } else { rmax[s] = -2.f; rarg[s] = 0; }
  }

  for (int step = 0; step < NB; step++) {
    // 1. local argmax over my slots: key = (score | 511-r | cls)
    uint64_t best = 0;
#pragma unroll
    for (int s = 0; s < SLOTS; s++) {
      int r = s * 64 + lane;
      uint64_t key = ((uint64_t)f2ord(rmax[s]) << 32) |
                     ((uint64_t)(511 - r) << 16) | (uint64_t)rarg[s];
      if (key > best) best = key;
    }
    // 2. butterfly max across 64 lanes
#pragma unroll
    for (int off = 1; off < 64; off <<= 1) {
      uint64_t o = (uint64_t)__shfl_xor((unsigned long long)best, off, 64);
      if (o > best) best = o;
    }
    int b = 511 - (int)((best >> 16) & 0x1FF);
    int cls = (int)(best & 0xFFFF);
    // 3. fetch winner's overlap row (7 u64), lanes 0..6
    uint64_t wword = 0;
    if (lane < 7) wword = ov_bits[(((size_t)(b * NC + cls)) << 3) + lane];
    uint64_t ow[SLOTS];
#pragma unroll
    for (int s = 0; s < SLOTS; s++)
      ow[s] = (uint64_t)__shfl((unsigned long long)wword, s, 64);

    // 4. per-slot register updates
#pragma unroll
    for (int s = 0; s < SLOTS; s++) {
      int r = s * 64 + lane;
      bool bit = (ow[s] >> lane) & 1;
      if (r == b) {
        rmax[s] = -1.f; rarg[s] = 0;
        labels_g[b] = cls;
        out_preds[b] = (float)cls;
      } else if (bit) {
        scores[r * NC + cls] = 0.f;
        if (rarg[s] == cls) {
          // suppressed entry was this row's argmax -> exact rescan
          float bm = -2.f; int ba = 0;
          for (int c2 = 0; c2 < NC; c2++) {
            float vv = (c2 == cls) ? 0.f : scores[r * NC + c2];
            if (vv > bm) { bm = vv; ba = c2; }
          }
          rmax[s] = bm; rarg[s] = ba;
        } else if (rmax[s] < -0.5f) {
          rmax[s] = 0.f; rarg[s] = cls;        // dead-row resurrection
        } else if (rmax[s] == 0.f && cls < rarg[s]) {
          rarg[s] = cls;                        // zero tie -> min col
        }
      }
    }
    // 5. removal: keep global row exact (-1) for future rescans
    for (int c = lane; c < NC; c += 64) scores[b * NC + c] = -1.f;
  }
}

// ---------------------------------------------------------------------------
extern "C" void kernel_launch(void* const* d_in, const int* in_sizes, int n_in,
                              void* d_out, int out_size, void* d_ws, size_t ws_size,
                              hipStream_t stream) {
  const float* x            = (const float*)d_in[0];
  const float* logits       = (const float*)d_in[1];
  const float* pos_input    = (const float*)d_in[2];
  const float* boxes        = (const float*)d_in[3];
  const float* obj_embed_w  = (const float*)d_in[4];
  const float* obj_embed2_w = (const float*)d_in[5];
  const float* w_pos1       = (const float*)d_in[6];
  const float* b_pos1       = (const float*)d_in[7];
  const float* bn_gamma     = (const float*)d_in[8];
  const float* bn_beta      = (const float*)d_in[9];
  const float* bn_mean      = (const float*)d_in[10];
  const float* bn_var       = (const float*)d_in[11];
  const float* w_pos2       = (const float*)d_in[12];
  const float* b_pos2       = (const float*)d_in[13];
  const float* w_lin        = (const float*)d_in[14];
  const float* b_lin        = (const float*)d_in[15];
  const float* w_out        = (const float*)d_in[16];
  const float* b_out        = (const float*)d_in[17];
  const float* w_fc         = (const float*)d_in[18];
  const float* b_fc         = (const float*)d_in[19];

  float* ws         = (float*)d_ws;
  float* tail1      = ws;                              // 416*328 = 136448 f
  float* tail2      = tail1 + MPAD * TAILW;            // 136448 f
  float* hidden     = tail2 + MPAD * TAILW;            // 204800 f
  float* scores     = hidden + NB * DH;                // 60400 f
  float* row_max    = scores + NB * NC;                // 400 f
  uint32_t* row_arg = (uint32_t*)(row_max + NB);       // 400
  int* labels       = (int*)(row_arg + NB);            // 400 (+16 pad)
  // union region: split-K partials (8*400*512 f = 6.55 MB) before/after NMS;
  // ov_bits (3.87 MB) lives here between k_overlap and k_nms.
  float* uregion    = (float*)(labels + NB + 16);
  uint64_t* ov_bits = (uint64_t*)uregion;
  float* part       = uregion;

  float* out       = (float*)d_out;
  float* out_dists = out;                 // 400*151
  float* out_preds = out + NB * NC;       // 400
  float* out_edge  = out + NB * NC + NB;  // 400*512

  k_embed<<<MPAD, 256, 0, stream>>>(logits, obj_embed_w, pos_input, w_pos1, b_pos1,
                                    bn_gamma, bn_beta, bn_mean, bn_var, w_pos2, b_pos2,
                                    tail1, tail2);
  k_gemm_pk<<<dim3(8, 13, SPLITK), 256, 0, stream>>>(x, tail1, w_lin, part);
  k_sumparts<<<200, 256, 0, stream>>>(part, b_lin, hidden, 0);
  k_overlap<<<NC, 256, 0, stream>>>(boxes, ov_bits);
  k_dists<<<NB, 256, 0, stream>>>(hidden, w_out, b_out, out_dists, scores, row_max, row_arg);
  k_nms<<<1, 64, 0, stream>>>(ov_bits, scores, row_max, row_arg, labels, out_preds);
  k_tail2<<<NB, 256, 0, stream>>>(obj_embed2_w, labels, tail2);
  k_gemm_pk<<<dim3(8, 13, SPLITK), 256, 0, stream>>>(x, tail2, w_fc, part);
  k_sumparts<<<200, 256, 0, stream>>>(part, b_fc, out_edge, 1);
}

// Round 5
// 708.751 us; speedup vs baseline: 1.7718x; 1.4036x over previous
//
#include <hip/hip_runtime.h>
#include <hip/hip_bf16.h>
#include <stdint.h>

#define NB 400
#define NC 151
#define DX 4096
#define DE 200
#define DP 128
#define DH 512
#define KREP 4424   // 4096 + 200 + 128
#define TAILW 328   // DE + DP
#define MPAD 416    // 13*32 rows, padded
#define SPLITK 8
#define TILES 139   // ceil(4424/32), last tile is 8 wide
#define SLOTS 7     // 7*64 = 448 >= 400
#define SKSTRIDE 152

__device__ __forceinline__ uint32_t f2ord(float f) {
  uint32_t u = __float_as_uint(f);
  return (u & 0x80000000u) ? ~u : (u | 0x80000000u);
}

// ---------------------------------------------------------------------------
// k_embed: softmax(logits) @ obj_embed_w and pos path; writes packed tails.
// ---------------------------------------------------------------------------
__global__ __launch_bounds__(256) void k_embed(
    const float* __restrict__ logits, const float* __restrict__ obj_embed_w,
    const float* __restrict__ pos_input, const float* __restrict__ w_pos1,
    const float* __restrict__ b_pos1, const float* __restrict__ bn_gamma,
    const float* __restrict__ bn_beta, const float* __restrict__ bn_mean,
    const float* __restrict__ bn_var, const float* __restrict__ w_pos2,
    const float* __restrict__ b_pos2,
    float* __restrict__ tail1, float* __restrict__ tail2) {
  int r = blockIdx.x, t = threadIdx.x;
  if (r >= NB) {            // zero pad rows
    if (t < TAILW) { tail1[r * TAILW + t] = 0.f; tail2[r * TAILW + t] = 0.f; }
    return;
  }
  __shared__ float p[NC];
  __shared__ float red[256];
  __shared__ float hb[32];

  float v = (t < NC) ? logits[r * NC + t] : -INFINITY;
  red[t] = v; __syncthreads();
  for (int s = 128; s > 0; s >>= 1) { if (t < s) red[t] = fmaxf(red[t], red[t + s]); __syncthreads(); }
  float m = red[0]; __syncthreads();
  float e = (t < NC) ? expf(v - m) : 0.f;
  red[t] = e; __syncthreads();
  for (int s = 128; s > 0; s >>= 1) { if (t < s) red[t] += red[t + s]; __syncthreads(); }
  float sum = red[0];
  if (t < NC) p[t] = e / sum;

  if (t < 32) {
    float acc = b_pos1[t];
    for (int k = 0; k < 9; k++) acc += pos_input[r * 9 + k] * w_pos1[k * 32 + t];
    acc = (acc - bn_mean[t]) / sqrtf(bn_var[t] + 1e-5f) * bn_gamma[t] + bn_beta[t];
    hb[t] = acc;
  }
  __syncthreads();

  if (t < DE) {
    float acc = 0.f;
    for (int k = 0; k < NC; k++) acc += p[k] * obj_embed_w[k * DE + t];
    tail1[r * TAILW + t] = acc;
  }
  if (t < DP) {
    float acc = b_pos2[t];
    for (int k = 0; k < 32; k++) acc += hb[k] * w_pos2[k * DP + t];
    float pe = fmaxf(acc, 0.f);
    tail1[r * TAILW + DE + t] = pe;
    tail2[r * TAILW + t] = pe;
  }
}

// ---------------------------------------------------------------------------
// k_tail2: after NMS, fill tail2[:,128:328] = obj_embed2_w[labels[r]].
// ---------------------------------------------------------------------------
__global__ __launch_bounds__(256) void k_tail2(
    const float* __restrict__ emb2, const int* __restrict__ labels,
    float* __restrict__ tail2) {
  int r = blockIdx.x, t = threadIdx.x;
  if (t < DE) tail2[r * TAILW + DP + t] = emb2[labels[r] * DE + t];
}

// ---------------------------------------------------------------------------
// k_overlap: bit-packed IoU>=0.5 matrix. One block per class c.
// ---------------------------------------------------------------------------
__global__ __launch_bounds__(256) void k_overlap(
    const float* __restrict__ boxes, uint64_t* __restrict__ ov_bits) {
  int c = blockIdx.x;
  int t = threadIdx.x;
  __shared__ float4 bx[NB];
  const float4* bp4 = (const float4*)boxes;
  for (int j = t; j < NB; j += 256) bx[j] = bp4[j * NC + c];
  __syncthreads();

  int wave = t >> 6, lane = t & 63;
  for (int b = wave; b < NB; b += 4) {
    float4 A = bx[b];
    float areaA = (A.z - A.x + 1.f) * (A.w - A.y + 1.f);
    for (int chunk = 0; chunk < 7; chunk++) {
      int j = chunk * 64 + lane;
      bool ov = false;
      if (j < NB) {
        float4 B = bx[j];
        float x1 = fmaxf(A.x, B.x), y1 = fmaxf(A.y, B.y);
        float x2 = fminf(A.z, B.z), y2 = fminf(A.w, B.w);
        float iw = fmaxf(x2 - x1 + 1.f, 0.f), ih = fmaxf(y2 - y1 + 1.f, 0.f);
        float inter = iw * ih;
        float areaB = (B.z - B.x + 1.f) * (B.w - B.y + 1.f);
        float uni = areaA + areaB - inter;
        ov = (inter / uni) >= 0.5f;
      }
      uint64_t mask = __ballot(ov);
      if (lane == 0) ov_bits[((size_t)(b * NC + c) << 3) + chunk] = mask;
    }
  }
}

// ---------------------------------------------------------------------------
// k_gemm_pk: split-K partial GEMM, all-float4 loads, register prefetch.
// ---------------------------------------------------------------------------
__global__ __launch_bounds__(256) void k_gemm_pk(
    const float* __restrict__ x, const float* __restrict__ tail,
    const float* __restrict__ w, float* __restrict__ part) {
  __shared__ __align__(16) float As[32][36];
  __shared__ __align__(16) float Bs[32][68];
  int tid = threadIdx.x;
  int n0 = blockIdx.x * 64, m0 = blockIdx.y * 32;
  int z = blockIdx.z;
  int tbeg = (z * TILES) / SPLITK, tend = ((z + 1) * TILES) / SPLITK;
  int ty = tid >> 4, tx = tid & 15;
  int a_r = tid >> 3, a_c = (tid & 7) << 2;
  int b_r = tid >> 4, b_c = (tid & 15) << 2;
  float4 acc0 = {0, 0, 0, 0}, acc1 = {0, 0, 0, 0};

  auto loadA = [&](int t) -> float4 {
    int k = t * 32 + a_c;
    int row = m0 + a_r;
    float4 v = {0, 0, 0, 0};
    if (k < KREP) {
      if (k < DX) { if (row < NB) v = *(const float4*)&x[(size_t)row * DX + k]; }
      else v = *(const float4*)&tail[row * TAILW + (k - DX)];
    }
    return v;
  };
  auto loadB = [&](int t, int roff) -> float4 {
    int k = t * 32 + b_r + roff;
    float4 v = {0, 0, 0, 0};
    if (k < KREP) v = *(const float4*)&w[(size_t)k * DH + n0 + b_c];
    return v;
  };

  float4 pa = loadA(tbeg), pb0 = loadB(tbeg, 0), pb1 = loadB(tbeg, 16);
  for (int t = tbeg; t < tend; t++) {
    __syncthreads();
    *(float4*)&As[a_r][a_c] = pa;
    *(float4*)&Bs[b_r][b_c] = pb0;
    *(float4*)&Bs[b_r + 16][b_c] = pb1;
    __syncthreads();
    if (t + 1 < tend) { pa = loadA(t + 1); pb0 = loadB(t + 1, 0); pb1 = loadB(t + 1, 16); }
#pragma unroll
    for (int k4 = 0; k4 < 8; k4++) {
      float4 a0 = *(float4*)&As[ty * 2][k4 * 4];
      float4 a1 = *(float4*)&As[ty * 2 + 1][k4 * 4];
#pragma unroll
      for (int j = 0; j < 4; j++) {
        float4 bv = *(float4*)&Bs[k4 * 4 + j][tx * 4];
        float av0 = (&a0.x)[j], av1 = (&a1.x)[j];
        acc0.x += av0 * bv.x; acc0.y += av0 * bv.y; acc0.z += av0 * bv.z; acc0.w += av0 * bv.w;
        acc1.x += av1 * bv.x; acc1.y += av1 * bv.y; acc1.z += av1 * bv.z; acc1.w += av1 * bv.w;
      }
    }
  }
  int row0 = m0 + ty * 2, col = n0 + tx * 4;
  float* base = part + (size_t)z * NB * DH;
  if (row0 < NB)     *(float4*)&base[row0 * DH + col] = acc0;
  if (row0 + 1 < NB) *(float4*)&base[(row0 + 1) * DH + col] = acc1;
}

// ---------------------------------------------------------------------------
// k_sumparts: out = sum_z part[z] + bias (opt relu), fixed order.
// ---------------------------------------------------------------------------
__global__ __launch_bounds__(256) void k_sumparts(
    const float* __restrict__ part, const float* __restrict__ bias,
    float* __restrict__ outp, int relu) {
  int i = blockIdx.x * 256 + threadIdx.x;
  const float4* p4 = (const float4*)part;
  float4 r = {0, 0, 0, 0};
#pragma unroll
  for (int zz = 0; zz < SPLITK; zz++) {
    float4 p = p4[(size_t)zz * 51200 + i];
    r.x += p.x; r.y += p.y; r.z += p.z; r.w += p.w;
  }
  float4 bv = ((const float4*)bias)[i & 127];
  r.x += bv.x; r.y += bv.y; r.z += bv.z; r.w += bv.w;
  if (relu) {
    r.x = fmaxf(r.x, 0.f); r.y = fmaxf(r.y, 0.f);
    r.z = fmaxf(r.z, 0.f); r.w = fmaxf(r.w, 0.f);
  }
  ((float4*)outp)[i] = r;
}

// ---------------------------------------------------------------------------
// k_dists: obj_dists = hidden @ w_out + b_out -> d_out; softmax; emit per-row
// SORTED key list (value desc, col asc) for cols 1..150:
// skeys[r][rank] = (f2ord(v)<<17) | ((511-r)<<8) | col.  Col 0 (score -1) is
// excluded; it can never be a row argmax while any other entry >= 0 exists.
// ---------------------------------------------------------------------------
__global__ __launch_bounds__(256) void k_dists(
    const float* __restrict__ hidden, const float* __restrict__ w_out,
    const float* __restrict__ b_out, float* __restrict__ out_dists,
    uint64_t* __restrict__ skeys) {
  int r = blockIdx.x, t = threadIdx.x;
  __shared__ float h[DH];
  __shared__ float red[256];
  __shared__ float sval[NC];
  h[t] = hidden[r * DH + t];
  h[t + 256] = hidden[r * DH + t + 256];
  __syncthreads();

  float acc = -INFINITY;
  if (t < NC) {
    acc = b_out[t];
    for (int k = 0; k < DH; k++) acc += h[k] * w_out[k * NC + t];
    out_dists[r * NC + t] = acc;
  }
  red[t] = (t < NC) ? acc : -INFINITY; __syncthreads();
  for (int s = 128; s > 0; s >>= 1) { if (t < s) red[t] = fmaxf(red[t], red[t + s]); __syncthreads(); }
  float mx = red[0]; __syncthreads();
  float e = (t < NC) ? expf(acc - mx) : 0.f;
  red[t] = e; __syncthreads();
  for (int s = 128; s > 0; s >>= 1) { if (t < s) red[t] += red[t + s]; __syncthreads(); }
  float sum = red[0];
  if (t < NC) sval[t] = e / sum;
  __syncthreads();

  if (t >= 1 && t < NC) {
    float v = sval[t];
    int rank = 0;
    for (int c2 = 1; c2 < NC; c2++) {
      float v2 = sval[c2];
      rank += (v2 > v) || (v2 == v && c2 < t);
    }
    skeys[(size_t)r * SKSTRIDE + rank] =
        ((uint64_t)f2ord(v) << 17) | ((uint64_t)(511 - r) << 8) | (uint64_t)t;
  }
}

// ---------------------------------------------------------------------------
// k_nms: single-wave greedy NMS, zero global stores in the loop (labels only).
// Per-row state in registers: candidate key, 151-bit suppression mask,
// sorted-list depth, removed flag, resurrection min-col. Top-2 speculation:
// pick2 valid iff its entry untouched by pick1 (all updates are decreasing).
// ---------------------------------------------------------------------------
__global__ __launch_bounds__(64) void k_nms(
    const uint64_t* __restrict__ ov_bits, const uint64_t* __restrict__ skeys,
    int* __restrict__ labels_g, float* __restrict__ out_preds) {
  int lane = threadIdx.x;
  uint64_t cand[SLOTS];
  uint64_t supp0[SLOTS], supp1[SLOTS], supp2[SLOTS];
  int depth[SLOTS];
  bool removed[SLOTS];
  int reszmin[SLOTS];

#pragma unroll
  for (int s = 0; s < SLOTS; s++) {
    int r = s * 64 + lane;
    supp0[s] = supp1[s] = supp2[s] = 0;
    depth[s] = 0; removed[s] = false; reszmin[s] = 255;
    if (r < NB) {
      cand[s] = skeys[(size_t)r * SKSTRIDE];
      labels_g[r] = 0; out_preds[r] = 0.f;
    } else cand[s] = 0;
  }

  // apply one pick (b,c) with its overlap row ow[]
  auto apply = [&](int b, int c, const uint64_t* ow) {
#pragma unroll
    for (int s = 0; s < SLOTS; s++) {
      int r = s * 64 + lane;
      if (r == b) {
        removed[s] = true; reszmin[s] = 255;
        cand[s] = ((uint64_t)0x407FFFFFu << 17) | ((uint64_t)(511 - r) << 8);
        labels_g[b] = c; out_preds[b] = (float)c;
      } else if ((ow[s] >> lane) & 1) {
        if (removed[s]) {
          if (c < reszmin[s]) reszmin[s] = c;   // resurrection: 0.0 at min col
          cand[s] = ((uint64_t)0x80000000u << 17) | ((uint64_t)(511 - r) << 8)
                    | (uint64_t)reszmin[s];
        } else {
          uint64_t bit = 1ull << (c & 63);
          if (c < 64) supp0[s] |= bit; else if (c < 128) supp1[s] |= bit; else supp2[s] |= bit;
          if ((int)(cand[s] & 0xFF) == c) {
            // pop sorted list past suppressed cols
            int d = depth[s] + 1;
            uint64_t k = 0;
            for (; d < 150; d++) {
              k = skeys[(size_t)r * SKSTRIDE + d];
              int col = (int)(k & 0xFF);
              uint64_t m = (col < 64) ? supp0[s] : ((col < 128) ? supp1[s] : supp2[s]);
              if (!((m >> (col & 63)) & 1)) break;
            }
            if (d >= 150)   // all cols 1..150 suppressed -> (0.0, col 1)
              k = ((uint64_t)0x80000000u << 17) | ((uint64_t)(511 - r) << 8) | 1ull;
            depth[s] = d; cand[s] = k;
          }
        }
      }
    }
  };

  int picked = 0;
  while (picked < NB) {
    // local top-2 over my slots
    uint64_t k1 = 0, k2 = 0;
#pragma unroll
    for (int s = 0; s < SLOTS; s++) {
      uint64_t k = cand[s];
      if (k > k1) { k2 = k1; k1 = k; } else if (k > k2) k2 = k;
    }
    // butterfly top-2 merge (disjoint groups each round -> exact)
#pragma unroll
    for (int off = 1; off < 64; off <<= 1) {
      uint64_t o1 = (uint64_t)__shfl_xor((unsigned long long)k1, off, 64);
      uint64_t o2 = (uint64_t)__shfl_xor((unsigned long long)k2, off, 64);
      uint64_t hi = k1 > o1 ? k1 : o1;
      uint64_t lo = k1 > o1 ? o1 : k1;
      uint64_t m2 = k2 > o2 ? k2 : o2;
      k1 = hi; k2 = lo > m2 ? lo : m2;
    }
    int b1 = 511 - (int)((k1 >> 8) & 0x1FF), c1 = (int)(k1 & 0xFF);
    int b2 = 511 - (int)((k2 >> 8) & 0x1FF), c2 = (int)(k2 & 0xFF);

    // fetch both winners' overlap rows concurrently
    uint64_t wv = 0;
    if (lane < 7)                 wv = ov_bits[(((size_t)(b1 * NC + c1)) << 3) + lane];
    else if (lane >= 8 && lane < 15) wv = ov_bits[(((size_t)(b2 * NC + c2)) << 3) + (lane - 8)];
    uint64_t ow1[SLOTS], ow2[SLOTS];
#pragma unroll
    for (int s = 0; s < SLOTS; s++) {
      ow1[s] = (uint64_t)__shfl((unsigned long long)wv, s, 64);
      ow2[s] = (uint64_t)__shfl((unsigned long long)wv, s + 8, 64);
    }
    // pick2 valid iff its entry untouched by pick1 (rows always distinct)
    bool sec = (picked + 1 < NB) &&
               !((c2 == c1) && ((ow1[b2 >> 6] >> (b2 & 63)) & 1));

    apply(b1, c1, ow1);
    picked++;
    if (sec) { apply(b2, c2, ow2); picked++; }
  }
}

// ---------------------------------------------------------------------------
extern "C" void kernel_launch(void* const* d_in, const int* in_sizes, int n_in,
                              void* d_out, int out_size, void* d_ws, size_t ws_size,
                              hipStream_t stream) {
  const float* x            = (const float*)d_in[0];
  const float* logits       = (const float*)d_in[1];
  const float* pos_input    = (const float*)d_in[2];
  const float* boxes        = (const float*)d_in[3];
  const float* obj_embed_w  = (const float*)d_in[4];
  const float* obj_embed2_w = (const float*)d_in[5];
  const float* w_pos1       = (const float*)d_in[6];
  const float* b_pos1       = (const float*)d_in[7];
  const float* bn_gamma     = (const float*)d_in[8];
  const float* bn_beta      = (const float*)d_in[9];
  const float* bn_mean      = (const float*)d_in[10];
  const float* bn_var       = (const float*)d_in[11];
  const float* w_pos2       = (const float*)d_in[12];
  const float* b_pos2       = (const float*)d_in[13];
  const float* w_lin        = (const float*)d_in[14];
  const float* b_lin        = (const float*)d_in[15];
  const float* w_out        = (const float*)d_in[16];
  const float* b_out        = (const float*)d_in[17];
  const float* w_fc         = (const float*)d_in[18];
  const float* b_fc         = (const float*)d_in[19];

  float* ws         = (float*)d_ws;
  float* tail1      = ws;                              // 416*328 = 136448 f
  float* tail2      = tail1 + MPAD * TAILW;            // 136448 f
  float* hidden     = tail2 + MPAD * TAILW;            // 204800 f
  int* labels       = (int*)(hidden + NB * DH);        // 400 (+16 pad) -> even
  uint64_t* skeys   = (uint64_t*)(labels + NB + 16);   // 400*152 u64 = 486 KB
  // union region: split-K partials (6.55 MB) before/after NMS; ov_bits
  // (484 KB) lives here between k_overlap and k_nms.
  float* uregion    = (float*)(skeys + NB * SKSTRIDE);
  uint64_t* ov_bits = (uint64_t*)uregion;
  float* part       = uregion;

  float* out       = (float*)d_out;
  float* out_dists = out;                 // 400*151
  float* out_preds = out + NB * NC;       // 400
  float* out_edge  = out + NB * NC + NB;  // 400*512

  k_embed<<<MPAD, 256, 0, stream>>>(logits, obj_embed_w, pos_input, w_pos1, b_pos1,
                                    bn_gamma, bn_beta, bn_mean, bn_var, w_pos2, b_pos2,
                                    tail1, tail2);
  k_gemm_pk<<<dim3(8, 13, SPLITK), 256, 0, stream>>>(x, tail1, w_lin, part);
  k_sumparts<<<200, 256, 0, stream>>>(part, b_lin, hidden, 0);
  k_overlap<<<NC, 256, 0, stream>>>(boxes, ov_bits);
  k_dists<<<NB, 256, 0, stream>>>(hidden, w_out, b_out, out_dists, skeys);
  k_nms<<<1, 64, 0, stream>>>(ov_bits, skeys, labels, out_preds);
  k_tail2<<<NB, 256, 0, stream>>>(obj_embed2_w, labels, tail2);
  k_gemm_pk<<<dim3(8, 13, SPLITK), 256, 0, stream>>>(x, tail2, w_fc, part);
  k_sumparts<<<200, 256, 0, stream>>>(part, b_fc, out_edge, 1);
}

// Round 6
// 627.507 us; speedup vs baseline: 2.0012x; 1.1295x over previous
//
#include <hip/hip_runtime.h>
#include <hip/hip_bf16.h>
#include <stdint.h>

#define NB 400
#define NC 151
#define DX 4096
#define DE 200
#define DP 128
#define DH 512
#define KREP 4424   // 4096 + 200 + 128
#define TAILW 328   // DE + DP
#define MPAD 416    // 13*32 rows, padded
#define SPLITK 8
#define TILES1 139  // ceil(4424/32) - GEMM1 full K
#define TILES2 132  // 4224/32     - GEMM2a label-independent K
#define SLOTS 7     // 7*64 = 448 >= 400
#define SKSTRIDE 152

__device__ __forceinline__ uint32_t f2ord(float f) {
  uint32_t u = __float_as_uint(f);
  return (u & 0x80000000u) ? ~u : (u | 0x80000000u);
}

// ---------------------------------------------------------------------------
// k_embed: softmax(logits) @ obj_embed_w and pos path -> packed tail1 =
// [obj_embed(200) | pos_embed(128)]. Rows 400..415 zero (pad for float4).
// ---------------------------------------------------------------------------
__global__ __launch_bounds__(256) void k_embed(
    const float* __restrict__ logits, const float* __restrict__ obj_embed_w,
    const float* __restrict__ pos_input, const float* __restrict__ w_pos1,
    const float* __restrict__ b_pos1, const float* __restrict__ bn_gamma,
    const float* __restrict__ bn_beta, const float* __restrict__ bn_mean,
    const float* __restrict__ bn_var, const float* __restrict__ w_pos2,
    const float* __restrict__ b_pos2, float* __restrict__ tail1) {
  int r = blockIdx.x, t = threadIdx.x;
  if (r >= NB) {
    if (t < TAILW) tail1[r * TAILW + t] = 0.f;
    return;
  }
  __shared__ float p[NC];
  __shared__ float red[256];
  __shared__ float hb[32];

  float v = (t < NC) ? logits[r * NC + t] : -INFINITY;
  red[t] = v; __syncthreads();
  for (int s = 128; s > 0; s >>= 1) { if (t < s) red[t] = fmaxf(red[t], red[t + s]); __syncthreads(); }
  float m = red[0]; __syncthreads();
  float e = (t < NC) ? expf(v - m) : 0.f;
  red[t] = e; __syncthreads();
  for (int s = 128; s > 0; s >>= 1) { if (t < s) red[t] += red[t + s]; __syncthreads(); }
  float sum = red[0];
  if (t < NC) p[t] = e / sum;

  if (t < 32) {
    float acc = b_pos1[t];
    for (int k = 0; k < 9; k++) acc += pos_input[r * 9 + k] * w_pos1[k * 32 + t];
    acc = (acc - bn_mean[t]) / sqrtf(bn_var[t] + 1e-5f) * bn_gamma[t] + bn_beta[t];
    hb[t] = acc;
  }
  __syncthreads();

  if (t < DE) {
    float acc = 0.f;
    for (int k = 0; k < NC; k++) acc += p[k] * obj_embed_w[k * DE + t];
    tail1[r * TAILW + t] = acc;
  }
  if (t < DP) {
    float acc = b_pos2[t];
    for (int k = 0; k < 32; k++) acc += hb[k] * w_pos2[k * DP + t];
    tail1[r * TAILW + DE + t] = fmaxf(acc, 0.f);
  }
}

// ---------------------------------------------------------------------------
// gemm_body: split-K partial GEMM tile. A = [x(4096) | tail-segment]; tile
// 32(M)x64(N), BK=32, 2x4 microtile, register prefetch. toff selects the
// tail mapping (0: full tail1; 200: pos-only segment for GEMM2a).
// ---------------------------------------------------------------------------
__device__ __forceinline__ void gemm_body(
    const float* __restrict__ x, const float* __restrict__ tail,
    const float* __restrict__ w, float* __restrict__ part,
    int bid, int tiles, int toff) {
  __shared__ __align__(16) float As[32][36];
  __shared__ __align__(16) float Bs[32][68];
  int tid = threadIdx.x;
  int n0 = (bid & 7) * 64, m0 = ((bid >> 3) % 13) * 32;
  int z = bid / 104;
  int tbeg = (z * tiles) / SPLITK, tend = ((z + 1) * tiles) / SPLITK;
  int ty = tid >> 4, tx = tid & 15;
  int a_r = tid >> 3, a_c = (tid & 7) << 2;
  int b_r = tid >> 4, b_c = (tid & 15) << 2;
  float4 acc0 = {0, 0, 0, 0}, acc1 = {0, 0, 0, 0};

  auto loadA = [&](int t) -> float4 {
    int k = t * 32 + a_c;
    int row = m0 + a_r;
    float4 v = {0, 0, 0, 0};
    if (k < KREP) {
      if (k < DX) { if (row < NB) v = *(const float4*)&x[(size_t)row * DX + k]; }
      else v = *(const float4*)&tail[row * TAILW + toff + (k - DX)];
    }
    return v;
  };
  auto loadB = [&](int t, int roff) -> float4 {
    int k = t * 32 + b_r + roff;
    float4 v = {0, 0, 0, 0};
    if (k < KREP) v = *(const float4*)&w[(size_t)k * DH + n0 + b_c];
    return v;
  };

  float4 pa = loadA(tbeg), pb0 = loadB(tbeg, 0), pb1 = loadB(tbeg, 16);
  for (int t = tbeg; t < tend; t++) {
    __syncthreads();
    *(float4*)&As[a_r][a_c] = pa;
    *(float4*)&Bs[b_r][b_c] = pb0;
    *(float4*)&Bs[b_r + 16][b_c] = pb1;
    __syncthreads();
    if (t + 1 < tend) { pa = loadA(t + 1); pb0 = loadB(t + 1, 0); pb1 = loadB(t + 1, 16); }
#pragma unroll
    for (int k4 = 0; k4 < 8; k4++) {
      float4 a0 = *(float4*)&As[ty * 2][k4 * 4];
      float4 a1 = *(float4*)&As[ty * 2 + 1][k4 * 4];
#pragma unroll
      for (int j = 0; j < 4; j++) {
        float4 bv = *(float4*)&Bs[k4 * 4 + j][tx * 4];
        float av0 = (&a0.x)[j], av1 = (&a1.x)[j];
        acc0.x += av0 * bv.x; acc0.y += av0 * bv.y; acc0.z += av0 * bv.z; acc0.w += av0 * bv.w;
        acc1.x += av1 * bv.x; acc1.y += av1 * bv.y; acc1.z += av1 * bv.z; acc1.w += av1 * bv.w;
      }
    }
  }
  int row0 = m0 + ty * 2, col = n0 + tx * 4;
  float* base = part + (size_t)z * NB * DH;
  if (row0 < NB)     *(float4*)&base[row0 * DH + col] = acc0;
  if (row0 + 1 < NB) *(float4*)&base[(row0 + 1) * DH + col] = acc1;
}

// ---------------------------------------------------------------------------
// k_g1ov: blocks 0..831 = GEMM1 partials (A=[x|tail1], w_lin); blocks
// 832..982 = IoU>=0.5 bit matrix per class.
// ---------------------------------------------------------------------------
__global__ __launch_bounds__(256) void k_g1ov(
    const float* __restrict__ x, const float* __restrict__ tail1,
    const float* __restrict__ w_lin, float* __restrict__ part,
    const float* __restrict__ boxes, uint64_t* __restrict__ ov_bits) {
  int bid = blockIdx.x;
  if (bid >= 832) {
    int c = bid - 832;
    int t = threadIdx.x;
    __shared__ float4 bx[NB];
    const float4* bp4 = (const float4*)boxes;
    for (int j = t; j < NB; j += 256) bx[j] = bp4[j * NC + c];
    __syncthreads();
    int wave = t >> 6, lane = t & 63;
    for (int b = wave; b < NB; b += 4) {
      float4 A = bx[b];
      float areaA = (A.z - A.x + 1.f) * (A.w - A.y + 1.f);
      for (int chunk = 0; chunk < 7; chunk++) {
        int j = chunk * 64 + lane;
        bool ov = false;
        if (j < NB) {
          float4 B = bx[j];
          float x1 = fmaxf(A.x, B.x), y1 = fmaxf(A.y, B.y);
          float x2 = fminf(A.z, B.z), y2 = fminf(A.w, B.w);
          float iw = fmaxf(x2 - x1 + 1.f, 0.f), ih = fmaxf(y2 - y1 + 1.f, 0.f);
          float inter = iw * ih;
          float areaB = (B.z - B.x + 1.f) * (B.w - B.y + 1.f);
          ov = (inter / (areaA + areaB - inter)) >= 0.5f;
        }
        uint64_t mask = __ballot(ov);
        if (lane == 0) ov_bits[((size_t)(b * NC + c) << 3) + chunk] = mask;
      }
    }
    return;
  }
  gemm_body(x, tail1, w_lin, part, bid, TILES1, 0);
}

// ---------------------------------------------------------------------------
// k_dists: hidden row = sum of 8 GEMM1 partials + b_lin (in LDS, no global
// roundtrip); obj_dists = hidden @ w_out + b_out -> d_out; softmax; emit
// per-row SORTED key list (value desc, col asc), cols 1..150:
// skeys[r][rank] = (f2ord(v)<<17) | ((511-r)<<8) | col.
// ---------------------------------------------------------------------------
__global__ __launch_bounds__(256) void k_dists(
    const float* __restrict__ part, const float* __restrict__ b_lin,
    const float* __restrict__ w_out, const float* __restrict__ b_out,
    float* __restrict__ out_dists, uint64_t* __restrict__ skeys) {
  int r = blockIdx.x, t = threadIdx.x;
  __shared__ float h[DH];
  __shared__ float red[256];
  __shared__ float sval[NC];
  float s0 = b_lin[t], s1 = b_lin[t + 256];
#pragma unroll
  for (int z = 0; z < SPLITK; z++) {
    const float* pr = part + ((size_t)z * NB + r) * DH;
    s0 += pr[t]; s1 += pr[t + 256];
  }
  h[t] = s0; h[t + 256] = s1;
  __syncthreads();

  float acc = -INFINITY;
  if (t < NC) {
    acc = b_out[t];
    for (int k = 0; k < DH; k++) acc += h[k] * w_out[k * NC + t];
    out_dists[r * NC + t] = acc;
  }
  red[t] = (t < NC) ? acc : -INFINITY; __syncthreads();
  for (int s = 128; s > 0; s >>= 1) { if (t < s) red[t] = fmaxf(red[t], red[t + s]); __syncthreads(); }
  float mx = red[0]; __syncthreads();
  float e = (t < NC) ? expf(acc - mx) : 0.f;
  red[t] = e; __syncthreads();
  for (int s = 128; s > 0; s >>= 1) { if (t < s) red[t] += red[t + s]; __syncthreads(); }
  float sum = red[0];
  if (t < NC) sval[t] = e / sum;
  __syncthreads();

  if (t >= 1 && t < NC) {
    float v = sval[t];
    int rank = 0;
    for (int c2 = 1; c2 < NC; c2++) {
      float v2 = sval[c2];
      rank += (v2 > v) || (v2 == v && c2 < t);
    }
    skeys[(size_t)r * SKSTRIDE + rank] =
        ((uint64_t)f2ord(v) << 17) | ((uint64_t)(511 - r) << 8) | (uint64_t)t;
  }
}

// ---------------------------------------------------------------------------
// k_nms_g2a: block 0 wave 0 = greedy NMS with top-4 speculation; blocks
// 1..832 = GEMM2a partials over K in [0,4224) (label-independent part of
// edge_ctx), hidden under the serial NMS latency.
// Speculation validity: pick j applies iff value strictly > 0.0 (so no
// resurrection 0.0-key can outrank it) and no earlier pick i touched its
// entry (c_i==c_j && ov_i[b_j]). Apply prefix up to first invalid.
// ---------------------------------------------------------------------------
__global__ __launch_bounds__(256) void k_nms_g2a(
    const uint64_t* __restrict__ ov_bits, const uint64_t* __restrict__ skeys,
    int* __restrict__ labels_g, float* __restrict__ out_preds,
    const float* __restrict__ x, const float* __restrict__ tail1,
    const float* __restrict__ w_fc, float* __restrict__ part) {
  if (blockIdx.x > 0) {
    gemm_body(x, tail1, w_fc, part, blockIdx.x - 1, TILES2, DE);
    return;
  }
  if (threadIdx.x >= 64) return;
  int lane = threadIdx.x;
  uint64_t cand[SLOTS];
  uint64_t supp0[SLOTS], supp1[SLOTS], supp2[SLOTS];
  int depth[SLOTS];
  bool removed[SLOTS];
  int reszmin[SLOTS];

#pragma unroll
  for (int s = 0; s < SLOTS; s++) {
    int r = s * 64 + lane;
    supp0[s] = supp1[s] = supp2[s] = 0;
    depth[s] = 0; removed[s] = false; reszmin[s] = 255;
    if (r < NB) {
      cand[s] = skeys[(size_t)r * SKSTRIDE];
      labels_g[r] = 0; out_preds[r] = 0.f;
    } else cand[s] = 0;
  }

  auto apply = [&](int b, int c, const uint64_t* ow) {
#pragma unroll
    for (int s = 0; s < SLOTS; s++) {
      int r = s * 64 + lane;
      if (r == b) {
        removed[s] = true; reszmin[s] = 255;
        cand[s] = ((uint64_t)0x407FFFFFu << 17) | ((uint64_t)(511 - r) << 8);
        labels_g[b] = c; out_preds[b] = (float)c;
      } else if ((ow[s] >> lane) & 1) {
        if (removed[s]) {
          if (c < reszmin[s]) reszmin[s] = c;
          cand[s] = ((uint64_t)0x80000000u << 17) | ((uint64_t)(511 - r) << 8)
                    | (uint64_t)reszmin[s];
        } else {
          uint64_t bit = 1ull << (c & 63);
          if (c < 64) supp0[s] |= bit; else if (c < 128) supp1[s] |= bit; else supp2[s] |= bit;
          if ((int)(cand[s] & 0xFF) == c) {
            int d = depth[s] + 1;
            uint64_t k = 0;
            for (; d < 150; d++) {
              k = skeys[(size_t)r * SKSTRIDE + d];
              int col = (int)(k & 0xFF);
              uint64_t mm = (col < 64) ? supp0[s] : ((col < 128) ? supp1[s] : supp2[s]);
              if (!((mm >> (col & 63)) & 1)) break;
            }
            if (d >= 150)
              k = ((uint64_t)0x80000000u << 17) | ((uint64_t)(511 - r) << 8) | 1ull;
            depth[s] = d; cand[s] = k;
          }
        }
      }
    }
  };

  auto cswap = [](uint64_t& a, uint64_t& b) {
    uint64_t hi = a > b ? a : b, lo = a > b ? b : a; a = hi; b = lo;
  };

  int picked = 0;
  while (picked < NB) {
    // local top-4 over my slots (sorted desc)
    uint64_t k0 = 0, k1 = 0, k2 = 0, k3 = 0;
#pragma unroll
    for (int s = 0; s < SLOTS; s++) {
      uint64_t v = cand[s];
      if (v > k0)      { k3 = k2; k2 = k1; k1 = k0; k0 = v; }
      else if (v > k1) { k3 = k2; k2 = k1; k1 = v; }
      else if (v > k2) { k3 = k2; k2 = v; }
      else if (v > k3) { k3 = v; }
    }
    // butterfly top-4 merge (bitonic half-clean + sort4 per round)
#pragma unroll
    for (int off = 1; off < 64; off <<= 1) {
      uint64_t p0 = (uint64_t)__shfl_xor((unsigned long long)k0, off, 64);
      uint64_t p1 = (uint64_t)__shfl_xor((unsigned long long)k1, off, 64);
      uint64_t p2 = (uint64_t)__shfl_xor((unsigned long long)k2, off, 64);
      uint64_t p3 = (uint64_t)__shfl_xor((unsigned long long)k3, off, 64);
      uint64_t t0 = k0 > p3 ? k0 : p3;
      uint64_t t1 = k1 > p2 ? k1 : p2;
      uint64_t t2 = k2 > p1 ? k2 : p1;
      uint64_t t3 = k3 > p0 ? k3 : p0;
      cswap(t0, t2); cswap(t1, t3); cswap(t0, t1); cswap(t2, t3);
      k0 = t0; k1 = t1; k2 = t2; k3 = t3;
    }
    int b0 = 511 - (int)((k0 >> 8) & 0x1FF), c0 = (int)(k0 & 0xFF);
    int b1 = 511 - (int)((k1 >> 8) & 0x1FF), c1 = (int)(k1 & 0xFF);
    int b2 = 511 - (int)((k2 >> 8) & 0x1FF), c2 = (int)(k2 & 0xFF);
    int b3 = 511 - (int)((k3 >> 8) & 0x1FF), c3 = (int)(k3 & 0xFF);
    int npick = NB - picked; if (npick > 4) npick = 4;

    // fetch the npick winners' overlap rows concurrently (lane i*8+w -> word w of pick i)
    int pi = lane >> 3, pw = lane & 7;
    uint64_t wv = 0;
    if (pi < npick && pw < 7) {
      int bb = (pi == 0) ? b0 : (pi == 1) ? b1 : (pi == 2) ? b2 : b3;
      int cc = (pi == 0) ? c0 : (pi == 1) ? c1 : (pi == 2) ? c2 : c3;
      wv = ov_bits[(((size_t)(bb * NC + cc)) << 3) + pw];
    }
    auto ovb = [&](int ii, int bj) -> bool {   // bit bj of pick ii's row (collective)
      bool f = ((lane >> 3) == ii) && ((lane & 7) == (bj >> 6)) && ((wv >> (bj & 63)) & 1);
      return __ballot(f) != 0ull;
    };
    uint32_t v1 = (uint32_t)(k1 >> 17), v2 = (uint32_t)(k2 >> 17), v3 = (uint32_t)(k3 >> 17);
    int napply = 1;
    if (npick >= 2 && v1 > 0x80000000u && !(c1 == c0 && ovb(0, b1))) {
      napply = 2;
      if (npick >= 3 && v2 > 0x80000000u &&
          !(c2 == c0 && ovb(0, b2)) && !(c2 == c1 && ovb(1, b2))) {
        napply = 3;
        if (npick >= 4 && v3 > 0x80000000u &&
            !(c3 == c0 && ovb(0, b3)) && !(c3 == c1 && ovb(1, b3)) &&
            !(c3 == c2 && ovb(2, b3)))
          napply = 4;
      }
    }

    uint64_t ow[SLOTS];
#pragma unroll
    for (int s = 0; s < SLOTS; s++) ow[s] = (uint64_t)__shfl((unsigned long long)wv, s, 64);
    apply(b0, c0, ow);
    if (napply >= 2) {
#pragma unroll
      for (int s = 0; s < SLOTS; s++) ow[s] = (uint64_t)__shfl((unsigned long long)wv, 8 + s, 64);
      apply(b1, c1, ow);
    }
    if (napply >= 3) {
#pragma unroll
      for (int s = 0; s < SLOTS; s++) ow[s] = (uint64_t)__shfl((unsigned long long)wv, 16 + s, 64);
      apply(b2, c2, ow);
    }
    if (napply >= 4) {
#pragma unroll
      for (int s = 0; s < SLOTS; s++) ow[s] = (uint64_t)__shfl((unsigned long long)wv, 24 + s, 64);
      apply(b3, c3, ow);
    }
    picked += napply;
  }
}

// ---------------------------------------------------------------------------
// k_final: edge_ctx = relu( GEMM2a-partials + emb2[labels] @ w_fc[4224:] +
// b_fc ). Grid (8 n, 13 m); 32x64 tile over K=200 with label-gathered A.
// ---------------------------------------------------------------------------
__global__ __launch_bounds__(256) void k_final(
    const float* __restrict__ emb2, const int* __restrict__ labels,
    const float* __restrict__ w_fc, const float* __restrict__ part,
    const float* __restrict__ b_fc, float* __restrict__ out_edge) {
  __shared__ __align__(16) float As[32][36];
  __shared__ __align__(16) float Bs[32][68];
  int tid = threadIdx.x;
  int n0 = blockIdx.x * 64, m0 = blockIdx.y * 32;
  int ty = tid >> 4, tx = tid & 15;
  int a_r = tid >> 3, a_c = (tid & 7) << 2;
  int b_r = tid >> 4, b_c = (tid & 15) << 2;
  float4 acc0 = {0, 0, 0, 0}, acc1 = {0, 0, 0, 0};
  int row_a = m0 + a_r;
  int lab = (row_a < NB) ? labels[row_a] : 0;

  auto loadA = [&](int t) -> float4 {
    int kk = t * 32 + a_c;
    float4 v = {0, 0, 0, 0};
    if (kk < DE && row_a < NB) v = *(const float4*)&emb2[(size_t)lab * DE + kk];
    return v;
  };
  auto loadB = [&](int t, int roff) -> float4 {
    int kk = t * 32 + b_r + roff;
    float4 v = {0, 0, 0, 0};
    if (kk < DE) v = *(const float4*)&w_fc[(size_t)(DX + DP + kk) * DH + n0 + b_c];
    return v;
  };

  float4 pa = loadA(0), pb0 = loadB(0, 0), pb1 = loadB(0, 16);
  for (int t = 0; t < 7; t++) {   // 7 tiles cover K=200 (guards handle tail)
    __syncthreads();
    *(float4*)&As[a_r][a_c] = pa;
    *(float4*)&Bs[b_r][b_c] = pb0;
    *(float4*)&Bs[b_r + 16][b_c] = pb1;
    __syncthreads();
    if (t + 1 < 7) { pa = loadA(t + 1); pb0 = loadB(t + 1, 0); pb1 = loadB(t + 1, 16); }
#pragma unroll
    for (int k4 = 0; k4 < 8; k4++) {
      float4 a0 = *(float4*)&As[ty * 2][k4 * 4];
      float4 a1 = *(float4*)&As[ty * 2 + 1][k4 * 4];
#pragma unroll
      for (int j = 0; j < 4; j++) {
        float4 bv = *(float4*)&Bs[k4 * 4 + j][tx * 4];
        float av0 = (&a0.x)[j], av1 = (&a1.x)[j];
        acc0.x += av0 * bv.x; acc0.y += av0 * bv.y; acc0.z += av0 * bv.z; acc0.w += av0 * bv.w;
        acc1.x += av1 * bv.x; acc1.y += av1 * bv.y; acc1.z += av1 * bv.z; acc1.w += av1 * bv.w;
      }
    }
  }
  int row0 = m0 + ty * 2, col = n0 + tx * 4;
#pragma unroll
  for (int z = 0; z < SPLITK; z++) {
    if (row0 < NB) {
      float4 p = *(const float4*)&part[((size_t)z * NB + row0) * DH + col];
      acc0.x += p.x; acc0.y += p.y; acc0.z += p.z; acc0.w += p.w;
    }
    if (row0 + 1 < NB) {
      float4 p = *(const float4*)&part[((size_t)z * NB + row0 + 1) * DH + col];
      acc1.x += p.x; acc1.y += p.y; acc1.z += p.z; acc1.w += p.w;
    }
  }
  float4 bv = *(const float4*)&b_fc[col];
  if (row0 < NB) {
    float4 r;
    r.x = fmaxf(acc0.x + bv.x, 0.f); r.y = fmaxf(acc0.y + bv.y, 0.f);
    r.z = fmaxf(acc0.z + bv.z, 0.f); r.w = fmaxf(acc0.w + bv.w, 0.f);
    *(float4*)&out_edge[row0 * DH + col] = r;
  }
  if (row0 + 1 < NB) {
    float4 r;
    r.x = fmaxf(acc1.x + bv.x, 0.f); r.y = fmaxf(acc1.y + bv.y, 0.f);
    r.z = fmaxf(acc1.z + bv.z, 0.f); r.w = fmaxf(acc1.w + bv.w, 0.f);
    *(float4*)&out_edge[(row0 + 1) * DH + col] = r;
  }
}

// ---------------------------------------------------------------------------
extern "C" void kernel_launch(void* const* d_in, const int* in_sizes, int n_in,
                              void* d_out, int out_size, void* d_ws, size_t ws_size,
                              hipStream_t stream) {
  const float* x            = (const float*)d_in[0];
  const float* logits       = (const float*)d_in[1];
  const float* pos_input    = (const float*)d_in[2];
  const float* boxes        = (const float*)d_in[3];
  const float* obj_embed_w  = (const float*)d_in[4];
  const float* obj_embed2_w = (const float*)d_in[5];
  const float* w_pos1       = (const float*)d_in[6];
  const float* b_pos1       = (const float*)d_in[7];
  const float* bn_gamma     = (const float*)d_in[8];
  const float* bn_beta      = (const float*)d_in[9];
  const float* bn_mean      = (const float*)d_in[10];
  const float* bn_var       = (const float*)d_in[11];
  const float* w_pos2       = (const float*)d_in[12];
  const float* b_pos2       = (const float*)d_in[13];
  const float* w_lin        = (const float*)d_in[14];
  const float* b_lin        = (const float*)d_in[15];
  const float* w_out        = (const float*)d_in[16];
  const float* b_out        = (const float*)d_in[17];
  const float* w_fc         = (const float*)d_in[18];
  const float* b_fc         = (const float*)d_in[19];

  float* ws         = (float*)d_ws;
  float* tail1      = ws;                              // 416*328 = 136448 f
  int* labels       = (int*)(tail1 + MPAD * TAILW);    // 416 ints (even offset)
  uint64_t* skeys   = (uint64_t*)(labels + MPAD);      // 400*152 u64
  uint64_t* ov_bits = skeys + (size_t)NB * SKSTRIDE;   // 400*151*8 u64
  float* part       = (float*)(ov_bits + (size_t)NB * NC * 8);  // 8*400*512 f

  float* out       = (float*)d_out;
  float* out_dists = out;                 // 400*151
  float* out_preds = out + NB * NC;       // 400
  float* out_edge  = out + NB * NC + NB;  // 400*512

  k_embed<<<MPAD, 256, 0, stream>>>(logits, obj_embed_w, pos_input, w_pos1, b_pos1,
                                    bn_gamma, bn_beta, bn_mean, bn_var, w_pos2, b_pos2,
                                    tail1);
  k_g1ov<<<983, 256, 0, stream>>>(x, tail1, w_lin, part, boxes, ov_bits);
  k_dists<<<NB, 256, 0, stream>>>(part, b_lin, w_out, b_out, out_dists, skeys);
  k_nms_g2a<<<833, 256, 0, stream>>>(ov_bits, skeys, labels, out_preds,
                                     x, tail1, w_fc, part);
  k_final<<<dim3(8, 13), 256, 0, stream>>>(obj_embed2_w, labels, w_fc, part,
                                           b_fc, out_edge);
}